// Round 1
// 740.584 us; speedup vs baseline: 1.3113x; 1.3113x over previous
//
#include <hip/hip_runtime.h>
#include <math.h>

// Pipeline: pred (f32, unchanged) | prev->bf16 halo transpose (ptcvt) ->
// MFMA upsample (parity-class tap-GEMM, writes channel-last bf16 U_t directly) ->
// MFMA tap-GEMM convs on channel-last bf16 (f32 accum), conv0 init from tsdf
// bias volume V, conv2 fused split-tree scatter (f32 out).
#define NBLK 64
#define SUBTREE_FLOATS (512ull*32ull*1728ull)   // 28,311,552

typedef __attribute__((ext_vector_type(8))) short bf16x8;   // 8 bf16 (4 VGPR)
typedef __attribute__((ext_vector_type(4))) float f32x4;    // MFMA acc

__device__ __forceinline__ unsigned short f2b(float f) {    // f32->bf16 RNE
    unsigned u = __float_as_uint(f);
    u = u + 0x7FFFu + ((u >> 16) & 1u);
    return (unsigned short)(u >> 16);
}
__device__ __forceinline__ float b2f(unsigned short h) {
    return __uint_as_float(((unsigned)h) << 16);
}
__device__ __forceinline__ float relu_bn(float acc, float g, float b) {
    float s = g * rsqrtf(1.0f + 1e-5f);
    float v = acc * s + b;
    return v > 0.f ? v : 0.f;
}

// ---------------- prediction path (f32, verified R4-R6) ----------------
__global__ __launch_bounds__(128, 2)
void pred_p0(const float* __restrict__ prev, const float* __restrict__ w,
             const float* __restrict__ g, const float* __restrict__ b,
             float* __restrict__ h0) {
    int blk = blockIdx.x;              // n*16 + co
    int n = blk >> 4, co = blk & 15;
    int t = threadIdx.x;
    __shared__ float wlds[864];
    for (int i = t; i < 864; i += 128) wlds[i] = w[co * 864 + i];
    __syncthreads();
    __shared__ float pz5[10 * 10 * 5];
    if (t < 100) {
        int oy = t / 10, ox = t % 10;
        float acc[10];
        #pragma unroll
        for (int i = 0; i < 10; i++) acc[i] = 0.f;
        const float* pb = prev + (size_t)n * 32 * 1728;
        for (int ci = 0; ci < 32; ci++) {
            float wr[27];
            #pragma unroll
            for (int j = 0; j < 27; j++) wr[j] = wlds[ci * 27 + j];
            const float* pc = pb + ci * 1728;
            #pragma unroll
            for (int ky = 0; ky < 3; ky++) {
                #pragma unroll
                for (int kx = 0; kx < 3; kx++) {
                    const float* col = pc + (oy + ky) * 12 + (ox + kx);
                    #pragma unroll
                    for (int j = 0; j < 12; j++) {
                        float u = col[j * 144];
                        #pragma unroll
                        for (int kz = 0; kz < 3; kz++) {
                            int zz = j - kz;
                            if (zz >= 0 && zz < 10)
                                acc[zz] += u * wr[kz * 9 + ky * 3 + kx];
                        }
                    }
                }
            }
        }
        float sc = g[co] * rsqrtf(1.0f + 1e-5f);
        float bi = b[co];
        #pragma unroll
        for (int p = 0; p < 5; p++) {
            float a0 = acc[2 * p]     * sc + bi; a0 = a0 > 0.f ? a0 : 0.f;
            float a1 = acc[2 * p + 1] * sc + bi; a1 = a1 > 0.f ? a1 : 0.f;
            pz5[(oy * 10 + ox) * 5 + p] = fmaxf(a0, a1);
        }
    }
    __syncthreads();
    if (t < 125) {
        int pz = t / 25, py = (t / 5) % 5, px = t % 5;
        float m = -INFINITY;
        #pragma unroll
        for (int dy = 0; dy < 2; dy++)
        #pragma unroll
        for (int dx = 0; dx < 2; dx++)
            m = fmaxf(m, pz5[((2 * py + dy) * 10 + 2 * px + dx) * 5 + pz]);
        h0[(n * 16 + co) * 125 + pz * 25 + py * 5 + px] = m;
    }
}

__global__ void pred_p1(const float* __restrict__ h0, const float* __restrict__ w,
                        const float* __restrict__ g, const float* __restrict__ b,
                        const float* __restrict__ wlin, const float* __restrict__ blin,
                        float* __restrict__ pred_out) {
    int n = blockIdx.x;
    __shared__ float conv[216];
    __shared__ float pooled[8];
    int t = threadIdx.x;
    if (t < 216) {
        int co = t / 27, r = t % 27;
        int oz = r / 9, oy = (r / 3) % 3, ox = r % 3;
        float acc = 0.f;
        for (int ci = 0; ci < 16; ci++) {
            const float* hc = h0 + (n * 16 + ci) * 125 + oz * 25 + oy * 5 + ox;
            const float* wc = w + (co * 16 + ci) * 27;
            #pragma unroll
            for (int kz = 0; kz < 3; kz++)
            #pragma unroll
            for (int ky = 0; ky < 3; ky++)
            #pragma unroll
            for (int kx = 0; kx < 3; kx++)
                acc += hc[kz * 25 + ky * 5 + kx] * wc[kz * 9 + ky * 3 + kx];
        }
        conv[t] = relu_bn(acc, g[co], b[co]);
    }
    __syncthreads();
    if (t < 8) {
        float m = -INFINITY;
        for (int dz = 0; dz < 2; dz++)
        for (int dy = 0; dy < 2; dy++)
        for (int dx = 0; dx < 2; dx++)
            m = fmaxf(m, conv[t * 27 + dz * 9 + dy * 3 + dx]);
        pooled[t] = m;
    }
    __syncthreads();
    if (t < 3) {
        float acc = blin[t];
        #pragma unroll
        for (int j = 0; j < 8; j++) acc += pooled[j] * wlin[t * 8 + j];
        pred_out[n * 3 + t] = acc;
    }
}

// ---------------- prev -> channel-last bf16 with 1-voxel zero halo ----------------
// Pt[n][z+1][y+1][x+1][ci] bf16, padded dims 14^3 (indices 0 and 13 are zero).
__global__ __launch_bounds__(256)
void ptcvt(const float* __restrict__ prev, unsigned short* __restrict__ Pt) {
    int n = blockIdx.x;
    const float* pb = prev + (size_t)n * 32 * 1728;
    unsigned short* ob = Pt + (size_t)n * 2744 * 32;
    for (int pos = threadIdx.x; pos < 2744; pos += 256) {
        int x = pos % 14, y = (pos / 14) % 14, zz = pos / 196;
        ushort4* o = (ushort4*)(ob + (size_t)pos * 32);
        if (x >= 1 && x <= 12 && y >= 1 && y <= 12 && zz >= 1 && zz <= 12) {
            int src = (zz - 1) * 144 + (y - 1) * 12 + (x - 1);
            unsigned short v[32];
            #pragma unroll
            for (int ci = 0; ci < 32; ci++) v[ci] = f2b(pb[(size_t)ci * 1728 + src]);
            #pragma unroll
            for (int j = 0; j < 8; j++)
                o[j] = make_ushort4(v[4 * j], v[4 * j + 1], v[4 * j + 2], v[4 * j + 3]);
        } else {
            #pragma unroll
            for (int j = 0; j < 8; j++) o[j] = make_ushort4(0, 0, 0, 0);
        }
    }
}

// ---------------- upsample weight prep: wup[co][ci][64tap] -> WupT[tap][co][ci] bf16 ----
__global__ void wupprep(const float* __restrict__ wup, unsigned short* __restrict__ Wt) {
    int i = blockIdx.x * 256 + threadIdx.x;          // 64*32*32 = 65536
    int tap = i >> 10, rem = i & 1023, co = rem >> 5, ci = rem & 31;
    Wt[i] = f2b(wup[co * 2048 + ci * 64 + tap]);
}

// ---------------- MFMA upsample (ConvTranspose3d k=4 s=2 as parity tap-GEMM) ----------
// out[co][oz][oy][ox] = sum_{dz,dy,dx in {0,1}} sum_ci
//     W[co][ci][(pz+2dz)*16+(py+2dy)*4+(px+2dx)] * prev[ci][oz/2-dz][oy/2-dy][ox/2-dx]
// pz = oz&1 uniform per block (z-slice); each wave owns one (py,px) parity class:
// 13x13 = 169 positions = 11 lane-tiles. Boundary taps hit the zero halo in Pt.
// Writes U_t[nl][oz][oy*26+ox][32co] bf16 — the exact layout conv_mfma consumes.
__global__ __launch_bounds__(256, 2)
void ups_mfma(const unsigned short* __restrict__ Pt,
              const unsigned short* __restrict__ Wt,
              unsigned short* __restrict__ Ut, int n0)
{
    constexpr int TPW = 11;
    int z  = blockIdx.x % 26;
    int nl = blockIdx.x / 26;
    int lane = threadIdx.x & 63, wave = threadIdx.x >> 6;
    int ln = lane & 15, quad = lane >> 4;
    int pz = z & 1, izb = (z >> 1) + 1;              // padded z index of dz=0 tap
    int py = wave >> 1, px = wave & 1;               // this wave's (oy,ox) parity

    const unsigned short* pbase =
        Pt + (size_t)(n0 + nl) * 2744 * 32 + (size_t)izb * 196 * 32 + quad * 8;

    int nidx[TPW];
    const unsigned short* bptr[TPW];
    #pragma unroll
    for (int t = 0; t < TPW; t++) {
        int n = t * 16 + ln;
        nidx[t] = (n < 169) ? n : 169;               // 169 => inactive lane slot
        int nc = (n < 169) ? n : 168;
        int iy = nc / 13 + 1, ix = nc % 13 + 1;      // padded base (dy=dx=0 tap)
        bptr[t] = pbase + ((size_t)iy * 14 + ix) * 32;
    }
    f32x4 acc[TPW][2];
    #pragma unroll
    for (int t = 0; t < TPW; t++) {
        acc[t][0] = (f32x4){0.f, 0.f, 0.f, 0.f};
        acc[t][1] = (f32x4){0.f, 0.f, 0.f, 0.f};
    }

    #pragma unroll 1
    for (int tap = 0; tap < 8; tap++) {
        int dz = tap >> 2, dy = (tap >> 1) & 1, dx = tap & 1;
        int ptap = (pz + 2 * dz) * 16 + (py + 2 * dy) * 4 + (px + 2 * dx);
        const unsigned short* wp = Wt + ptap * 1024 + ln * 32 + quad * 8;
        bf16x8 Af0 = *(const bf16x8*)wp;             // co tile 0
        bf16x8 Af1 = *(const bf16x8*)(wp + 512);     // co tile 1
        int off = -((dz * 196 + dy * 14 + dx) * 32); // step back into the halo
        #pragma unroll
        for (int t = 0; t < TPW; t++) {
            bf16x8 Bf = *(const bf16x8*)(bptr[t] + off);
            acc[t][0] = __builtin_amdgcn_mfma_f32_16x16x32_bf16(Af0, Bf, acc[t][0], 0, 0, 0);
            acc[t][1] = __builtin_amdgcn_mfma_f32_16x16x32_bf16(Af1, Bf, acc[t][1], 0, 0, 0);
        }
    }

    #pragma unroll
    for (int t = 0; t < TPW; t++) {
        if (nidx[t] >= 169) continue;
        int oy = py + 2 * (nidx[t] / 13);
        int ox = px + 2 * (nidx[t] % 13);
        unsigned short* o = Ut +
            ((size_t)nl * 17576 + (size_t)z * 676 + oy * 26 + ox) * 32 + quad * 4;
        *(ushort4*)o = make_ushort4(f2b(acc[t][0][0]), f2b(acc[t][0][1]),
                                    f2b(acc[t][0][2]), f2b(acc[t][0][3]));
        *(ushort4*)(o + 16) = make_ushort4(f2b(acc[t][1][0]), f2b(acc[t][1][1]),
                                           f2b(acc[t][1][2]), f2b(acc[t][1][3]));
    }
}

// ---------------- weight prep: w[co][ci][27] f32 -> Wt[tap][co][ci] bf16 ----------
__global__ void wprep(const float* __restrict__ w, unsigned short* __restrict__ Wt,
                      int wstride) {
    int i = blockIdx.x * 256 + threadIdx.x;
    if (i >= 27648) return;
    int tap = i >> 10, rem = i & 1023, co = rem >> 5, ci = rem & 31;
    Wt[i] = f2b(w[co * wstride + ci * 27 + tap]);
}

// ---------------- tsdf bias volume: V[zz][yy][xx][co] bf16 (72^3) ----------------
__global__ __launch_bounds__(128)
void vkern(const float* __restrict__ tsdf, const float* __restrict__ w_c0,
           unsigned short* __restrict__ V) {
    int yy = blockIdx.x % 72, zz = blockIdx.x / 72;
    int xx = threadIdx.x;
    if (xx >= 72) return;
    float tv[27];
    #pragma unroll
    for (int kz = 0; kz < 3; kz++)
    #pragma unroll
    for (int ky = 0; ky < 3; ky++)
    #pragma unroll
    for (int kx = 0; kx < 3; kx++)
        tv[kz * 9 + ky * 3 + kx] = tsdf[(size_t)(zz + kz) * 5476 + (yy + ky) * 74 + (xx + kx)];
    unsigned short* o = V + (((size_t)zz * 72 + yy) * 72 + xx) * 32;
    for (int co = 0; co < 32; co++) {
        float a = 0.f;
        const float* wc = w_c0 + co * 891 + 864;   // tsdf channel (ci=32) taps
        #pragma unroll
        for (int j = 0; j < 27; j++) a += tv[j] * wc[j];
        o[co] = f2b(a);
    }
}

// ---------------- MFMA tap-GEMM conv ----------------
// out[co][z][y][x] = sum_{tap,ci} Wt[tap][co][ci] * in_t[z+kz][y+ky][x+kx][ci]
// MFMA 16x16x32 bf16: A[m=lane&15][k=quad*8+j], B[n=lane&15][k=quad*8+j],
// D[row=quad*4+reg][col=lane&15]  (m=co-in-tile, n=spatial, k=ci).
// MODE 0: bf16 ch-last out | 1: + acc init from V | 2: f32 split-tree scatter out
template<int SIN, int SOUT, int MODE, int TPW>
__global__ __launch_bounds__(256, 2)
void conv_mfma(const unsigned short* __restrict__ in_t,
               const unsigned short* __restrict__ Wt,
               const float* __restrict__ gg, const float* __restrict__ bb,
               unsigned short* __restrict__ out_t, float* __restrict__ out_f,
               const unsigned short* __restrict__ V, int n0)
{
    constexpr int NPOS = SOUT * SOUT;
    constexpr int NT = (NPOS + 15) / 16;
    int z  = blockIdx.x % SOUT;
    int nl = blockIdx.x / SOUT;
    int lane = threadIdx.x & 63, wave = threadIdx.x >> 6;
    int ln = lane & 15, quad = lane >> 4;

    int nidx[TPW], py[TPW], px[TPW];
    const unsigned short* bptr[TPW];
    const unsigned short* inb =
        in_t + (size_t)nl * SIN * SIN * SIN * 32 + (size_t)z * SIN * SIN * 32;
    #pragma unroll
    for (int t = 0; t < TPW; t++) {
        int ti = wave + 4 * t;
        int n = ti * 16 + ln;
        nidx[t] = (ti < NT && n < NPOS) ? n : NPOS;     // NPOS => inactive lane-tile
        int nc = (nidx[t] < NPOS) ? nidx[t] : (NPOS - 1);
        py[t] = nc / SOUT; px[t] = nc % SOUT;
        bptr[t] = inb + ((size_t)py[t] * SIN + px[t]) * 32 + quad * 8;
    }
    f32x4 acc[TPW][2];
    if constexpr (MODE == 1) {
        int n = n0 + nl;
        int A = (n >> 4) * 16, B = ((n >> 2) & 3) * 16, C = (n & 3) * 16;
        #pragma unroll
        for (int t = 0; t < TPW; t++) {
            const unsigned short* vp =
                V + (((size_t)(A + z) * 72 + (B + py[t])) * 72 + (C + px[t])) * 32 + quad * 4;
            ushort4 v0 = *(const ushort4*)vp;
            ushort4 v1 = *(const ushort4*)(vp + 16);
            acc[t][0][0] = b2f(v0.x); acc[t][0][1] = b2f(v0.y);
            acc[t][0][2] = b2f(v0.z); acc[t][0][3] = b2f(v0.w);
            acc[t][1][0] = b2f(v1.x); acc[t][1][1] = b2f(v1.y);
            acc[t][1][2] = b2f(v1.z); acc[t][1][3] = b2f(v1.w);
        }
    } else {
        #pragma unroll
        for (int t = 0; t < TPW; t++) {
            #pragma unroll
            for (int c = 0; c < 2; c++)
                acc[t][c] = (f32x4){0.f, 0.f, 0.f, 0.f};
        }
    }

    #pragma unroll 1
    for (int tap = 0; tap < 27; tap++) {
        int kz = tap / 9, ky = (tap % 9) / 3, kx = tap % 3;
        const unsigned short* wp = Wt + tap * 1024 + ln * 32 + quad * 8;
        bf16x8 Af0 = *(const bf16x8*)wp;            // co tile 0
        bf16x8 Af1 = *(const bf16x8*)(wp + 512);    // co tile 1 (+16co*32ci)
        size_t off = ((size_t)kz * SIN * SIN + (size_t)ky * SIN + kx) * 32;
        #pragma unroll
        for (int t = 0; t < TPW; t++) {
            bf16x8 Bf = *(const bf16x8*)(bptr[t] + off);
            acc[t][0] = __builtin_amdgcn_mfma_f32_16x16x32_bf16(Af0, Bf, acc[t][0], 0, 0, 0);
            acc[t][1] = __builtin_amdgcn_mfma_f32_16x16x32_bf16(Af1, Bf, acc[t][1], 0, 0, 0);
        }
    }

    int cobase = quad * 4;
    f32x4 g0 = *(const f32x4*)(gg + cobase);
    f32x4 g1 = *(const f32x4*)(gg + 16 + cobase);
    f32x4 b0 = *(const f32x4*)(bb + cobase);
    f32x4 b1 = *(const f32x4*)(bb + 16 + cobase);

    #pragma unroll
    for (int t = 0; t < TPW; t++) {
        if (nidx[t] >= NPOS) continue;
        float v0[4], v1[4];
        #pragma unroll
        for (int r = 0; r < 4; r++) {
            v0[r] = relu_bn(acc[t][0][r], g0[r], b0[r]);
            v1[r] = relu_bn(acc[t][1][r], g1[r], b1[r]);
        }
        if constexpr (MODE != 2) {
            unsigned short* o = out_t +
                ((size_t)nl * SOUT * SOUT * SOUT + (size_t)z * NPOS + nidx[t]) * 32 + cobase;
            *(ushort4*)o        = make_ushort4(f2b(v0[0]), f2b(v0[1]), f2b(v0[2]), f2b(v0[3]));
            *(ushort4*)(o + 16) = make_ushort4(f2b(v1[0]), f2b(v1[1]), f2b(v1[2]), f2b(v1[3]));
        } else {
            int n = n0 + nl;
            int oy = py[t], ox = px[t];
            #pragma unroll
            for (int za = 0; za < 2; za++) {
                int zz = z - za * 8; if (zz < 0 || zz >= 12) continue;
                #pragma unroll
                for (int yb = 0; yb < 2; yb++) {
                    int yy = oy - yb * 8; if (yy < 0 || yy >= 12) continue;
                    #pragma unroll
                    for (int xc = 0; xc < 2; xc++) {
                        int xx = ox - xc * 8; if (xx < 0 || xx >= 12) continue;
                        int s = za * 4 + yb * 2 + xc;
                        float* ob = out_f + ((size_t)n * 8 + s) * 32 * 1728
                                    + zz * 144 + yy * 12 + xx;
                        #pragma unroll
                        for (int r = 0; r < 4; r++) {
                            ob[(size_t)(cobase + r) * 1728]      = v0[r];
                            ob[(size_t)(16 + cobase + r) * 1728] = v1[r];
                        }
                    }
                }
            }
        }
    }
}

extern "C" void kernel_launch(void* const* d_in, const int* in_sizes, int n_in,
                              void* d_out, int out_size, void* d_ws, size_t ws_size,
                              hipStream_t stream) {
    const float* prev  = (const float*)d_in[0];
    const float* tsdf  = (const float*)d_in[1];
    const float* w_up  = (const float*)d_in[2];
    const float* w_c0  = (const float*)d_in[3];
    const float* g_c0  = (const float*)d_in[4];
    const float* b_c0  = (const float*)d_in[5];
    const float* w_c1  = (const float*)d_in[6];
    const float* g_c1  = (const float*)d_in[7];
    const float* b_c1  = (const float*)d_in[8];
    const float* w_c2  = (const float*)d_in[9];
    const float* g_c2  = (const float*)d_in[10];
    const float* b_c2  = (const float*)d_in[11];
    const float* w_p0  = (const float*)d_in[12];
    const float* g_p0  = (const float*)d_in[13];
    const float* b_p0  = (const float*)d_in[14];
    const float* w_p1  = (const float*)d_in[15];
    const float* g_p1  = (const float*)d_in[16];
    const float* b_p1  = (const float*)d_in[17];
    const float* w_lin = (const float*)d_in[18];
    const float* b_lin = (const float*)d_in[19];

    float* out = (float*)d_out;
    char* wsb  = (char*)d_ws;

    size_t off = 0;
    float* h0 = (float*)(wsb + off);            off += 512000;      // 64*16*125 f32
    unsigned short* Wt0 = (unsigned short*)(wsb + off); off += 55296;
    unsigned short* Wt1 = (unsigned short*)(wsb + off); off += 55296;
    unsigned short* Wt2 = (unsigned short*)(wsb + off); off += 55296;
    unsigned short* V   = (unsigned short*)(wsb + off); off += 23887872; // 72^3*32 bf16
    unsigned short* Pt  = (unsigned short*)(wsb + off); off += 11239424; // 64*14^3*32 bf16
    unsigned short* WupT= (unsigned short*)(wsb + off); off += 131072;   // 64*32*32 bf16
    size_t fixed = off;

    int chunk = 64;
    while (chunk > 1) {
        size_t need = fixed + (size_t)chunk *
            (1124864ull /*U_t*/ + 884736ull /*X0_t*/ + 681472ull /*X1_t*/);
        if (need <= ws_size) break;
        chunk >>= 1;
    }
    unsigned short* U_t = (unsigned short*)(wsb + off); off += (size_t)chunk * 1124864;
    unsigned short* X0t = (unsigned short*)(wsb + off); off += (size_t)chunk * 884736;
    unsigned short* X1t = (unsigned short*)(wsb + off);

    // prediction path + preps
    pred_p0<<<64 * 16, 128, 0, stream>>>(prev, w_p0, g_p0, b_p0, h0);
    pred_p1<<<64, 256, 0, stream>>>(h0, w_p1, g_p1, b_p1, w_lin, b_lin,
                                    out + SUBTREE_FLOATS);
    ptcvt<<<64, 256, 0, stream>>>(prev, Pt);
    wupprep<<<256, 256, 0, stream>>>(w_up, WupT);
    wprep<<<108, 256, 0, stream>>>(w_c0, Wt0, 891);
    wprep<<<108, 256, 0, stream>>>(w_c1, Wt1, 864);
    wprep<<<108, 256, 0, stream>>>(w_c2, Wt2, 864);
    vkern<<<72 * 72, 128, 0, stream>>>(tsdf, w_c0, V);

    for (int n0 = 0; n0 < NBLK; n0 += chunk) {
        ups_mfma<<<chunk * 26, 256, 0, stream>>>(Pt, WupT, U_t, n0);
        conv_mfma<26, 24, 1, 9><<<chunk * 24, 256, 0, stream>>>(
            U_t, Wt0, g_c0, b_c0, X0t, nullptr, V, n0);
        conv_mfma<24, 22, 0, 8><<<chunk * 22, 256, 0, stream>>>(
            X0t, Wt1, g_c1, b_c1, X1t, nullptr, nullptr, n0);
        conv_mfma<22, 20, 2, 7><<<chunk * 20, 256, 0, stream>>>(
            X1t, Wt2, g_c2, b_c2, nullptr, out, nullptr, n0);
    }
}

// Round 3
// 701.923 us; speedup vs baseline: 1.3836x; 1.0551x over previous
//
#include <hip/hip_runtime.h>
#include <math.h>

// Pipeline: pred (f32, unchanged) | prev->bf16 halo transpose (ptcvt) ->
// MFMA upsample (parity-class tap-GEMM, writes channel-last bf16 U_t directly) ->
// MFMA tap-GEMM convs on channel-last bf16 (f32 accum), conv0 init from tsdf
// bias volume V, conv2 fused split-tree scatter (f32 out).
// R2: XCD-bijective swizzle (same nl-range pinned to one XCD across all tap-GEMM
// kernels) + explicit tap+1 register prefetch pipeline in conv_mfma.
#define NBLK 64
#define SUBTREE_FLOATS (512ull*32ull*1728ull)   // 28,311,552

typedef __attribute__((ext_vector_type(8))) short bf16x8;   // 8 bf16 (4 VGPR)
typedef __attribute__((ext_vector_type(4))) float f32x4;    // MFMA acc

__device__ __forceinline__ unsigned short f2b(float f) {    // f32->bf16 RNE
    unsigned u = __float_as_uint(f);
    u = u + 0x7FFFu + ((u >> 16) & 1u);
    return (unsigned short)(u >> 16);
}
__device__ __forceinline__ float b2f(unsigned short h) {
    return __uint_as_float(((unsigned)h) << 16);
}
__device__ __forceinline__ float relu_bn(float acc, float g, float b) {
    float s = g * rsqrtf(1.0f + 1e-5f);
    float v = acc * s + b;
    return v > 0.f ? v : 0.f;
}
// XCD-bijective remap: contiguous lin-chunk per XCD (hw: XCD = blockIdx % 8).
__device__ __forceinline__ int xcd_lin() {
    int bid = blockIdx.x, nwg = gridDim.x;
    if ((nwg & 7) == 0) {
        int per = nwg >> 3;
        return (bid & 7) * per + (bid >> 3);
    }
    return bid;
}

// ---------------- prediction path (f32, verified R4-R6) ----------------
__global__ __launch_bounds__(128, 2)
void pred_p0(const float* __restrict__ prev, const float* __restrict__ w,
             const float* __restrict__ g, const float* __restrict__ b,
             float* __restrict__ h0) {
    int blk = blockIdx.x;              // n*16 + co
    int n = blk >> 4, co = blk & 15;
    int t = threadIdx.x;
    __shared__ float wlds[864];
    for (int i = t; i < 864; i += 128) wlds[i] = w[co * 864 + i];
    __syncthreads();
    __shared__ float pz5[10 * 10 * 5];
    if (t < 100) {
        int oy = t / 10, ox = t % 10;
        float acc[10];
        #pragma unroll
        for (int i = 0; i < 10; i++) acc[i] = 0.f;
        const float* pb = prev + (size_t)n * 32 * 1728;
        for (int ci = 0; ci < 32; ci++) {
            float wr[27];
            #pragma unroll
            for (int j = 0; j < 27; j++) wr[j] = wlds[ci * 27 + j];
            const float* pc = pb + ci * 1728;
            #pragma unroll
            for (int ky = 0; ky < 3; ky++) {
                #pragma unroll
                for (int kx = 0; kx < 3; kx++) {
                    const float* col = pc + (oy + ky) * 12 + (ox + kx);
                    #pragma unroll
                    for (int j = 0; j < 12; j++) {
                        float u = col[j * 144];
                        #pragma unroll
                        for (int kz = 0; kz < 3; kz++) {
                            int zz = j - kz;
                            if (zz >= 0 && zz < 10)
                                acc[zz] += u * wr[kz * 9 + ky * 3 + kx];
                        }
                    }
                }
            }
        }
        float sc = g[co] * rsqrtf(1.0f + 1e-5f);
        float bi = b[co];
        #pragma unroll
        for (int p = 0; p < 5; p++) {
            float a0 = acc[2 * p]     * sc + bi; a0 = a0 > 0.f ? a0 : 0.f;
            float a1 = acc[2 * p + 1] * sc + bi; a1 = a1 > 0.f ? a1 : 0.f;
            pz5[(oy * 10 + ox) * 5 + p] = fmaxf(a0, a1);
        }
    }
    __syncthreads();
    if (t < 125) {
        int pz = t / 25, py = (t / 5) % 5, px = t % 5;
        float m = -INFINITY;
        #pragma unroll
        for (int dy = 0; dy < 2; dy++)
        #pragma unroll
        for (int dx = 0; dx < 2; dx++)
            m = fmaxf(m, pz5[((2 * py + dy) * 10 + 2 * px + dx) * 5 + pz]);
        h0[(n * 16 + co) * 125 + pz * 25 + py * 5 + px] = m;
    }
}

__global__ void pred_p1(const float* __restrict__ h0, const float* __restrict__ w,
                        const float* __restrict__ g, const float* __restrict__ b,
                        const float* __restrict__ wlin, const float* __restrict__ blin,
                        float* __restrict__ pred_out) {
    int n = blockIdx.x;
    __shared__ float conv[216];
    __shared__ float pooled[8];
    int t = threadIdx.x;
    if (t < 216) {
        int co = t / 27, r = t % 27;
        int oz = r / 9, oy = (r / 3) % 3, ox = r % 3;
        float acc = 0.f;
        for (int ci = 0; ci < 16; ci++) {
            const float* hc = h0 + (n * 16 + ci) * 125 + oz * 25 + oy * 5 + ox;
            const float* wc = w + (co * 16 + ci) * 27;
            #pragma unroll
            for (int kz = 0; kz < 3; kz++)
            #pragma unroll
            for (int ky = 0; ky < 3; ky++)
            #pragma unroll
            for (int kx = 0; kx < 3; kx++)
                acc += hc[kz * 25 + ky * 5 + kx] * wc[kz * 9 + ky * 3 + kx];
        }
        conv[t] = relu_bn(acc, g[co], b[co]);
    }
    __syncthreads();
    if (t < 8) {
        float m = -INFINITY;
        for (int dz = 0; dz < 2; dz++)
        for (int dy = 0; dy < 2; dy++)
        for (int dx = 0; dx < 2; dx++)
            m = fmaxf(m, conv[t * 27 + dz * 9 + dy * 3 + dx]);
        pooled[t] = m;
    }
    __syncthreads();
    if (t < 3) {
        float acc = blin[t];
        #pragma unroll
        for (int j = 0; j < 8; j++) acc += pooled[j] * wlin[t * 8 + j];
        pred_out[n * 3 + t] = acc;
    }
}

// ---------------- prev -> channel-last bf16 with 1-voxel zero halo ----------------
// Pt[n][z+1][y+1][x+1][ci] bf16, padded dims 14^3 (indices 0 and 13 are zero).
__global__ __launch_bounds__(256)
void ptcvt(const float* __restrict__ prev, unsigned short* __restrict__ Pt) {
    int n = blockIdx.x;
    const float* pb = prev + (size_t)n * 32 * 1728;
    unsigned short* ob = Pt + (size_t)n * 2744 * 32;
    for (int pos = threadIdx.x; pos < 2744; pos += 256) {
        int x = pos % 14, y = (pos / 14) % 14, zz = pos / 196;
        ushort4* o = (ushort4*)(ob + (size_t)pos * 32);
        if (x >= 1 && x <= 12 && y >= 1 && y <= 12 && zz >= 1 && zz <= 12) {
            int src = (zz - 1) * 144 + (y - 1) * 12 + (x - 1);
            unsigned short v[32];
            #pragma unroll
            for (int ci = 0; ci < 32; ci++) v[ci] = f2b(pb[(size_t)ci * 1728 + src]);
            #pragma unroll
            for (int j = 0; j < 8; j++)
                o[j] = make_ushort4(v[4 * j], v[4 * j + 1], v[4 * j + 2], v[4 * j + 3]);
        } else {
            #pragma unroll
            for (int j = 0; j < 8; j++) o[j] = make_ushort4(0, 0, 0, 0);
        }
    }
}

// ---------------- upsample weight prep: wup[co][ci][64tap] -> WupT[tap][co][ci] bf16 ----
__global__ void wupprep(const float* __restrict__ wup, unsigned short* __restrict__ Wt) {
    int i = blockIdx.x * 256 + threadIdx.x;          // 64*32*32 = 65536
    int tap = i >> 10, rem = i & 1023, co = rem >> 5, ci = rem & 31;
    Wt[i] = f2b(wup[co * 2048 + ci * 64 + tap]);
}

// ---------------- MFMA upsample (ConvTranspose3d k=4 s=2 as parity tap-GEMM) ----------
// out[co][oz][oy][ox] = sum_{dz,dy,dx in {0,1}} sum_ci
//     W[co][ci][(pz+2dz)*16+(py+2dy)*4+(px+2dx)] * prev[ci][oz/2-dz][oy/2-dy][ox/2-dx]
// pz = oz&1 uniform per block (z-slice); each wave owns one (py,px) parity class:
// 13x13 = 169 positions = 11 lane-tiles. Boundary taps hit the zero halo in Pt.
// Writes U_t[nl][oz][oy*26+ox][32co] bf16 — the exact layout conv_mfma consumes.
__global__ __launch_bounds__(256, 2)
void ups_mfma(const unsigned short* __restrict__ Pt,
              const unsigned short* __restrict__ Wt,
              unsigned short* __restrict__ Ut, int n0)
{
    constexpr int TPW = 11;
    int lin = xcd_lin();
    int z  = lin % 26;
    int nl = lin / 26;
    int lane = threadIdx.x & 63, wave = threadIdx.x >> 6;
    int ln = lane & 15, quad = lane >> 4;
    int pz = z & 1, izb = (z >> 1) + 1;              // padded z index of dz=0 tap
    int py = wave >> 1, px = wave & 1;               // this wave's (oy,ox) parity

    const unsigned short* pbase =
        Pt + (size_t)(n0 + nl) * 2744 * 32 + (size_t)izb * 196 * 32 + quad * 8;

    int nidx[TPW];
    const unsigned short* bptr[TPW];
    #pragma unroll
    for (int t = 0; t < TPW; t++) {
        int n = t * 16 + ln;
        nidx[t] = (n < 169) ? n : 169;               // 169 => inactive lane slot
        int nc = (n < 169) ? n : 168;
        int iy = nc / 13 + 1, ix = nc % 13 + 1;      // padded base (dy=dx=0 tap)
        bptr[t] = pbase + ((size_t)iy * 14 + ix) * 32;
    }
    f32x4 acc[TPW][2];
    #pragma unroll
    for (int t = 0; t < TPW; t++) {
        acc[t][0] = (f32x4){0.f, 0.f, 0.f, 0.f};
        acc[t][1] = (f32x4){0.f, 0.f, 0.f, 0.f};
    }

    #pragma unroll 1
    for (int tap = 0; tap < 8; tap++) {
        int dz = tap >> 2, dy = (tap >> 1) & 1, dx = tap & 1;
        int ptap = (pz + 2 * dz) * 16 + (py + 2 * dy) * 4 + (px + 2 * dx);
        const unsigned short* wp = Wt + ptap * 1024 + ln * 32 + quad * 8;
        bf16x8 Af0 = *(const bf16x8*)wp;             // co tile 0
        bf16x8 Af1 = *(const bf16x8*)(wp + 512);     // co tile 1
        int off = -((dz * 196 + dy * 14 + dx) * 32); // step back into the halo
        #pragma unroll
        for (int t = 0; t < TPW; t++) {
            bf16x8 Bf = *(const bf16x8*)(bptr[t] + off);
            acc[t][0] = __builtin_amdgcn_mfma_f32_16x16x32_bf16(Af0, Bf, acc[t][0], 0, 0, 0);
            acc[t][1] = __builtin_amdgcn_mfma_f32_16x16x32_bf16(Af1, Bf, acc[t][1], 0, 0, 0);
        }
    }

    #pragma unroll
    for (int t = 0; t < TPW; t++) {
        if (nidx[t] >= 169) continue;
        int oy = py + 2 * (nidx[t] / 13);
        int ox = px + 2 * (nidx[t] % 13);
        unsigned short* o = Ut +
            ((size_t)nl * 17576 + (size_t)z * 676 + oy * 26 + ox) * 32 + quad * 4;
        *(ushort4*)o = make_ushort4(f2b(acc[t][0][0]), f2b(acc[t][0][1]),
                                    f2b(acc[t][0][2]), f2b(acc[t][0][3]));
        *(ushort4*)(o + 16) = make_ushort4(f2b(acc[t][1][0]), f2b(acc[t][1][1]),
                                           f2b(acc[t][1][2]), f2b(acc[t][1][3]));
    }
}

// ---------------- weight prep: w[co][ci][27] f32 -> Wt[tap][co][ci] bf16 ----------
__global__ void wprep(const float* __restrict__ w, unsigned short* __restrict__ Wt,
                      int wstride) {
    int i = blockIdx.x * 256 + threadIdx.x;
    if (i >= 27648) return;
    int tap = i >> 10, rem = i & 1023, co = rem >> 5, ci = rem & 31;
    Wt[i] = f2b(w[co * wstride + ci * 27 + tap]);
}

// ---------------- tsdf bias volume: V[zz][yy][xx][co] bf16 (72^3) ----------------
__global__ __launch_bounds__(128)
void vkern(const float* __restrict__ tsdf, const float* __restrict__ w_c0,
           unsigned short* __restrict__ V) {
    int yy = blockIdx.x % 72, zz = blockIdx.x / 72;
    int xx = threadIdx.x;
    if (xx >= 72) return;
    float tv[27];
    #pragma unroll
    for (int kz = 0; kz < 3; kz++)
    #pragma unroll
    for (int ky = 0; ky < 3; ky++)
    #pragma unroll
    for (int kx = 0; kx < 3; kx++)
        tv[kz * 9 + ky * 3 + kx] = tsdf[(size_t)(zz + kz) * 5476 + (yy + ky) * 74 + (xx + kx)];
    unsigned short* o = V + (((size_t)zz * 72 + yy) * 72 + xx) * 32;
    for (int co = 0; co < 32; co++) {
        float a = 0.f;
        const float* wc = w_c0 + co * 891 + 864;   // tsdf channel (ci=32) taps
        #pragma unroll
        for (int j = 0; j < 27; j++) a += tv[j] * wc[j];
        o[co] = f2b(a);
    }
}

// ---------------- MFMA tap-GEMM conv ----------------
// out[co][z][y][x] = sum_{tap,ci} Wt[tap][co][ci] * in_t[z+kz][y+ky][x+kx][ci]
// MFMA 16x16x32 bf16: A[m=lane&15][k=quad*8+j], B[n=lane&15][k=quad*8+j],
// D[row=quad*4+reg][col=lane&15]  (m=co-in-tile, n=spatial, k=ci).
// Tap loop is software-pipelined: tap+1 A/B fragments prefetched into registers
// during tap's MFMA cluster (loads are mostly L2-hit thanks to the XCD swizzle).
// MODE 0: bf16 ch-last out | 1: + acc init from V | 2: f32 split-tree scatter out
template<int SIN, int SOUT, int MODE, int TPW>
__global__ __launch_bounds__(256, 2)
void conv_mfma(const unsigned short* __restrict__ in_t,
               const unsigned short* __restrict__ Wt,
               const float* __restrict__ gg, const float* __restrict__ bb,
               unsigned short* __restrict__ out_t, float* __restrict__ out_f,
               const unsigned short* __restrict__ V, int n0)
{
    constexpr int NPOS = SOUT * SOUT;
    constexpr int NT = (NPOS + 15) / 16;
    int lin = xcd_lin();
    int z  = lin % SOUT;
    int nl = lin / SOUT;
    int lane = threadIdx.x & 63, wave = threadIdx.x >> 6;
    int ln = lane & 15, quad = lane >> 4;

    int nidx[TPW], py[TPW], px[TPW];
    const unsigned short* bptr[TPW];
    const unsigned short* inb =
        in_t + (size_t)nl * SIN * SIN * SIN * 32 + (size_t)z * SIN * SIN * 32;
    #pragma unroll
    for (int t = 0; t < TPW; t++) {
        int ti = wave + 4 * t;
        int n = ti * 16 + ln;
        nidx[t] = (ti < NT && n < NPOS) ? n : NPOS;     // NPOS => inactive lane-tile
        int nc = (nidx[t] < NPOS) ? nidx[t] : (NPOS - 1);
        py[t] = nc / SOUT; px[t] = nc % SOUT;
        bptr[t] = inb + ((size_t)py[t] * SIN + px[t]) * 32 + quad * 8;
    }
    f32x4 acc[TPW][2];
    if constexpr (MODE == 1) {
        int n = n0 + nl;
        int A = (n >> 4) * 16, B = ((n >> 2) & 3) * 16, C = (n & 3) * 16;
        #pragma unroll
        for (int t = 0; t < TPW; t++) {
            const unsigned short* vp =
                V + (((size_t)(A + z) * 72 + (B + py[t])) * 72 + (C + px[t])) * 32 + quad * 4;
            ushort4 v0 = *(const ushort4*)vp;
            ushort4 v1 = *(const ushort4*)(vp + 16);
            acc[t][0][0] = b2f(v0.x); acc[t][0][1] = b2f(v0.y);
            acc[t][0][2] = b2f(v0.z); acc[t][0][3] = b2f(v0.w);
            acc[t][1][0] = b2f(v1.x); acc[t][1][1] = b2f(v1.y);
            acc[t][1][2] = b2f(v1.z); acc[t][1][3] = b2f(v1.w);
        }
    } else {
        #pragma unroll
        for (int t = 0; t < TPW; t++) {
            #pragma unroll
            for (int c = 0; c < 2; c++)
                acc[t][c] = (f32x4){0.f, 0.f, 0.f, 0.f};
        }
    }

    // ---- software-pipelined tap loop ----
    const unsigned short* wp0 = Wt + ln * 32 + quad * 8;
    bf16x8 A0 = *(const bf16x8*)wp0;                 // tap 0 weights
    bf16x8 A1 = *(const bf16x8*)(wp0 + 512);
    bf16x8 B[TPW];
    #pragma unroll
    for (int t = 0; t < TPW; t++) B[t] = *(const bf16x8*)bptr[t];   // tap 0: off = 0

    #pragma unroll 1
    for (int tap = 0; tap < 27; tap++) {
        int nt = tap < 26 ? tap + 1 : 26;            // clamp: last iter reloads tap 26
        int kz = nt / 9, ky = (nt % 9) / 3, kx = nt % 3;
        const unsigned short* wp = Wt + nt * 1024 + ln * 32 + quad * 8;
        bf16x8 An0 = *(const bf16x8*)wp;
        bf16x8 An1 = *(const bf16x8*)(wp + 512);
        size_t off = ((size_t)kz * SIN * SIN + (size_t)ky * SIN + kx) * 32;
        bf16x8 Bn[TPW];
        #pragma unroll
        for (int t = 0; t < TPW; t++) Bn[t] = *(const bf16x8*)(bptr[t] + off);
        #pragma unroll
        for (int t = 0; t < TPW; t++) {
            acc[t][0] = __builtin_amdgcn_mfma_f32_16x16x32_bf16(A0, B[t], acc[t][0], 0, 0, 0);
            acc[t][1] = __builtin_amdgcn_mfma_f32_16x16x32_bf16(A1, B[t], acc[t][1], 0, 0, 0);
        }
        A0 = An0; A1 = An1;
        #pragma unroll
        for (int t = 0; t < TPW; t++) B[t] = Bn[t];
    }

    int cobase = quad * 4;
    f32x4 g0 = *(const f32x4*)(gg + cobase);
    f32x4 g1 = *(const f32x4*)(gg + 16 + cobase);
    f32x4 b0 = *(const f32x4*)(bb + cobase);
    f32x4 b1 = *(const f32x4*)(bb + 16 + cobase);

    #pragma unroll
    for (int t = 0; t < TPW; t++) {
        if (nidx[t] >= NPOS) continue;
        float v0[4], v1[4];
        #pragma unroll
        for (int r = 0; r < 4; r++) {
            v0[r] = relu_bn(acc[t][0][r], g0[r], b0[r]);
            v1[r] = relu_bn(acc[t][1][r], g1[r], b1[r]);
        }
        if constexpr (MODE != 2) {
            unsigned short* o = out_t +
                ((size_t)nl * SOUT * SOUT * SOUT + (size_t)z * NPOS + nidx[t]) * 32 + cobase;
            *(ushort4*)o        = make_ushort4(f2b(v0[0]), f2b(v0[1]), f2b(v0[2]), f2b(v0[3]));
            *(ushort4*)(o + 16) = make_ushort4(f2b(v1[0]), f2b(v1[1]), f2b(v1[2]), f2b(v1[3]));
        } else {
            int n = n0 + nl;
            int oy = py[t], ox = px[t];
            #pragma unroll
            for (int za = 0; za < 2; za++) {
                int zz = z - za * 8; if (zz < 0 || zz >= 12) continue;
                #pragma unroll
                for (int yb = 0; yb < 2; yb++) {
                    int yy = oy - yb * 8; if (yy < 0 || yy >= 12) continue;
                    #pragma unroll
                    for (int xc = 0; xc < 2; xc++) {
                        int xx = ox - xc * 8; if (xx < 0 || xx >= 12) continue;
                        int s = za * 4 + yb * 2 + xc;
                        float* ob = out_f + ((size_t)n * 8 + s) * 32 * 1728
                                    + zz * 144 + yy * 12 + xx;
                        #pragma unroll
                        for (int r = 0; r < 4; r++) {
                            ob[(size_t)(cobase + r) * 1728]      = v0[r];
                            ob[(size_t)(16 + cobase + r) * 1728] = v1[r];
                        }
                    }
                }
            }
        }
    }
}

extern "C" void kernel_launch(void* const* d_in, const int* in_sizes, int n_in,
                              void* d_out, int out_size, void* d_ws, size_t ws_size,
                              hipStream_t stream) {
    const float* prev  = (const float*)d_in[0];
    const float* tsdf  = (const float*)d_in[1];
    const float* w_up  = (const float*)d_in[2];
    const float* w_c0  = (const float*)d_in[3];
    const float* g_c0  = (const float*)d_in[4];
    const float* b_c0  = (const float*)d_in[5];
    const float* w_c1  = (const float*)d_in[6];
    const float* g_c1  = (const float*)d_in[7];
    const float* b_c1  = (const float*)d_in[8];
    const float* w_c2  = (const float*)d_in[9];
    const float* g_c2  = (const float*)d_in[10];
    const float* b_c2  = (const float*)d_in[11];
    const float* w_p0  = (const float*)d_in[12];
    const float* g_p0  = (const float*)d_in[13];
    const float* b_p0  = (const float*)d_in[14];
    const float* w_p1  = (const float*)d_in[15];
    const float* g_p1  = (const float*)d_in[16];
    const float* b_p1  = (const float*)d_in[17];
    const float* w_lin = (const float*)d_in[18];
    const float* b_lin = (const float*)d_in[19];

    float* out = (float*)d_out;
    char* wsb  = (char*)d_ws;

    size_t off = 0;
    float* h0 = (float*)(wsb + off);            off += 512000;      // 64*16*125 f32
    unsigned short* Wt0 = (unsigned short*)(wsb + off); off += 55296;
    unsigned short* Wt1 = (unsigned short*)(wsb + off); off += 55296;
    unsigned short* Wt2 = (unsigned short*)(wsb + off); off += 55296;
    unsigned short* V   = (unsigned short*)(wsb + off); off += 23887872; // 72^3*32 bf16
    unsigned short* Pt  = (unsigned short*)(wsb + off); off += 11239424; // 64*14^3*32 bf16
    unsigned short* WupT= (unsigned short*)(wsb + off); off += 131072;   // 64*32*32 bf16
    size_t fixed = off;

    int chunk = 64;
    while (chunk > 1) {
        size_t need = fixed + (size_t)chunk *
            (1124864ull /*U_t*/ + 884736ull /*X0_t*/ + 681472ull /*X1_t*/);
        if (need <= ws_size) break;
        chunk >>= 1;
    }
    unsigned short* U_t = (unsigned short*)(wsb + off); off += (size_t)chunk * 1124864;
    unsigned short* X0t = (unsigned short*)(wsb + off); off += (size_t)chunk * 884736;
    unsigned short* X1t = (unsigned short*)(wsb + off);

    // prediction path + preps
    pred_p0<<<64 * 16, 128, 0, stream>>>(prev, w_p0, g_p0, b_p0, h0);
    pred_p1<<<64, 256, 0, stream>>>(h0, w_p1, g_p1, b_p1, w_lin, b_lin,
                                    out + SUBTREE_FLOATS);
    ptcvt<<<64, 256, 0, stream>>>(prev, Pt);
    wupprep<<<256, 256, 0, stream>>>(w_up, WupT);
    wprep<<<108, 256, 0, stream>>>(w_c0, Wt0, 891);
    wprep<<<108, 256, 0, stream>>>(w_c1, Wt1, 864);
    wprep<<<108, 256, 0, stream>>>(w_c2, Wt2, 864);
    vkern<<<72 * 72, 128, 0, stream>>>(tsdf, w_c0, V);

    for (int n0 = 0; n0 < NBLK; n0 += chunk) {
        ups_mfma<<<chunk * 26, 256, 0, stream>>>(Pt, WupT, U_t, n0);
        conv_mfma<26, 24, 1, 9><<<chunk * 24, 256, 0, stream>>>(
            U_t, Wt0, g_c0, b_c0, X0t, nullptr, V, n0);
        conv_mfma<24, 22, 0, 8><<<chunk * 22, 256, 0, stream>>>(
            X0t, Wt1, g_c1, b_c1, X1t, nullptr, nullptr, n0);
        conv_mfma<22, 20, 2, 7><<<chunk * 20, 256, 0, stream>>>(
            X1t, Wt2, g_c2, b_c2, nullptr, out, nullptr, n0);
    }
}

// Round 4
// 649.982 us; speedup vs baseline: 1.4941x; 1.0799x over previous
//
#include <hip/hip_runtime.h>
#include <math.h>

// Pipeline: pred (f32) | prev->bf16 halo transpose (ptcvt) -> MFMA upsample ->
// MFMA tap-GEMM convs on channel-last bf16 (f32 accum), conv0 init from tsdf
// bias volume V, conv2 fused split-tree scatter (f32 out).
// R4: conv_mfma restructured for z-reuse: block owns a 4-deep z-slab x 2 tiles;
// loop (ky,kx) outer, input-z inner; each B fragment feeds 3 kz-taps x 4 z-outs.
// Loads per MFMA drop 2.7x (11/18 -> 18/48 per group). XCD swizzle kept.
#define NBLK 64
#define SUBTREE_FLOATS (512ull*32ull*1728ull)   // 28,311,552

typedef __attribute__((ext_vector_type(8))) short bf16x8;   // 8 bf16 (4 VGPR)
typedef __attribute__((ext_vector_type(4))) float f32x4;    // MFMA acc

__device__ __forceinline__ unsigned short f2b(float f) {    // f32->bf16 RNE
    unsigned u = __float_as_uint(f);
    u = u + 0x7FFFu + ((u >> 16) & 1u);
    return (unsigned short)(u >> 16);
}
__device__ __forceinline__ float b2f(unsigned short h) {
    return __uint_as_float(((unsigned)h) << 16);
}
__device__ __forceinline__ float relu_bn(float acc, float g, float b) {
    float s = g * rsqrtf(1.0f + 1e-5f);
    float v = acc * s + b;
    return v > 0.f ? v : 0.f;
}
// XCD-bijective remap: contiguous lin-chunk per XCD (hw: XCD = blockIdx % 8).
__device__ __forceinline__ int xcd_lin() {
    int bid = blockIdx.x, nwg = gridDim.x;
    if ((nwg & 7) == 0) {
        int per = nwg >> 3;
        return (bid & 7) * per + (bid >> 3);
    }
    return bid;
}

// ---------------- prediction path (f32, verified) ----------------
__global__ __launch_bounds__(128, 2)
void pred_p0(const float* __restrict__ prev, const float* __restrict__ w,
             const float* __restrict__ g, const float* __restrict__ b,
             float* __restrict__ h0) {
    int blk = blockIdx.x;              // n*16 + co
    int n = blk >> 4, co = blk & 15;
    int t = threadIdx.x;
    __shared__ float wlds[864];
    for (int i = t; i < 864; i += 128) wlds[i] = w[co * 864 + i];
    __syncthreads();
    __shared__ float pz5[10 * 10 * 5];
    if (t < 100) {
        int oy = t / 10, ox = t % 10;
        float acc[10];
        #pragma unroll
        for (int i = 0; i < 10; i++) acc[i] = 0.f;
        const float* pb = prev + (size_t)n * 32 * 1728;
        for (int ci = 0; ci < 32; ci++) {
            float wr[27];
            #pragma unroll
            for (int j = 0; j < 27; j++) wr[j] = wlds[ci * 27 + j];
            const float* pc = pb + ci * 1728;
            #pragma unroll
            for (int ky = 0; ky < 3; ky++) {
                #pragma unroll
                for (int kx = 0; kx < 3; kx++) {
                    const float* col = pc + (oy + ky) * 12 + (ox + kx);
                    #pragma unroll
                    for (int j = 0; j < 12; j++) {
                        float u = col[j * 144];
                        #pragma unroll
                        for (int kz = 0; kz < 3; kz++) {
                            int zz = j - kz;
                            if (zz >= 0 && zz < 10)
                                acc[zz] += u * wr[kz * 9 + ky * 3 + kx];
                        }
                    }
                }
            }
        }
        float sc = g[co] * rsqrtf(1.0f + 1e-5f);
        float bi = b[co];
        #pragma unroll
        for (int p = 0; p < 5; p++) {
            float a0 = acc[2 * p]     * sc + bi; a0 = a0 > 0.f ? a0 : 0.f;
            float a1 = acc[2 * p + 1] * sc + bi; a1 = a1 > 0.f ? a1 : 0.f;
            pz5[(oy * 10 + ox) * 5 + p] = fmaxf(a0, a1);
        }
    }
    __syncthreads();
    if (t < 125) {
        int pz = t / 25, py = (t / 5) % 5, px = t % 5;
        float m = -INFINITY;
        #pragma unroll
        for (int dy = 0; dy < 2; dy++)
        #pragma unroll
        for (int dx = 0; dx < 2; dx++)
            m = fmaxf(m, pz5[((2 * py + dy) * 10 + 2 * px + dx) * 5 + pz]);
        h0[(n * 16 + co) * 125 + pz * 25 + py * 5 + px] = m;
    }
}

__global__ void pred_p1(const float* __restrict__ h0, const float* __restrict__ w,
                        const float* __restrict__ g, const float* __restrict__ b,
                        const float* __restrict__ wlin, const float* __restrict__ blin,
                        float* __restrict__ pred_out) {
    int n = blockIdx.x;
    __shared__ float conv[216];
    __shared__ float pooled[8];
    int t = threadIdx.x;
    if (t < 216) {
        int co = t / 27, r = t % 27;
        int oz = r / 9, oy = (r / 3) % 3, ox = r % 3;
        float acc = 0.f;
        for (int ci = 0; ci < 16; ci++) {
            const float* hc = h0 + (n * 16 + ci) * 125 + oz * 25 + oy * 5 + ox;
            const float* wc = w + (co * 16 + ci) * 27;
            #pragma unroll
            for (int kz = 0; kz < 3; kz++)
            #pragma unroll
            for (int ky = 0; ky < 3; ky++)
            #pragma unroll
            for (int kx = 0; kx < 3; kx++)
                acc += hc[kz * 25 + ky * 5 + kx] * wc[kz * 9 + ky * 3 + kx];
        }
        conv[t] = relu_bn(acc, g[co], b[co]);
    }
    __syncthreads();
    if (t < 8) {
        float m = -INFINITY;
        for (int dz = 0; dz < 2; dz++)
        for (int dy = 0; dy < 2; dy++)
        for (int dx = 0; dx < 2; dx++)
            m = fmaxf(m, conv[t * 27 + dz * 9 + dy * 3 + dx]);
        pooled[t] = m;
    }
    __syncthreads();
    if (t < 3) {
        float acc = blin[t];
        #pragma unroll
        for (int j = 0; j < 8; j++) acc += pooled[j] * wlin[t * 8 + j];
        pred_out[n * 3 + t] = acc;
    }
}

// ---------------- prev -> channel-last bf16 with 1-voxel zero halo ----------------
__global__ __launch_bounds__(256)
void ptcvt(const float* __restrict__ prev, unsigned short* __restrict__ Pt) {
    int n = blockIdx.x;
    const float* pb = prev + (size_t)n * 32 * 1728;
    unsigned short* ob = Pt + (size_t)n * 2744 * 32;
    for (int pos = threadIdx.x; pos < 2744; pos += 256) {
        int x = pos % 14, y = (pos / 14) % 14, zz = pos / 196;
        ushort4* o = (ushort4*)(ob + (size_t)pos * 32);
        if (x >= 1 && x <= 12 && y >= 1 && y <= 12 && zz >= 1 && zz <= 12) {
            int src = (zz - 1) * 144 + (y - 1) * 12 + (x - 1);
            unsigned short v[32];
            #pragma unroll
            for (int ci = 0; ci < 32; ci++) v[ci] = f2b(pb[(size_t)ci * 1728 + src]);
            #pragma unroll
            for (int j = 0; j < 8; j++)
                o[j] = make_ushort4(v[4 * j], v[4 * j + 1], v[4 * j + 2], v[4 * j + 3]);
        } else {
            #pragma unroll
            for (int j = 0; j < 8; j++) o[j] = make_ushort4(0, 0, 0, 0);
        }
    }
}

// ---------------- upsample weight prep ----------------
__global__ void wupprep(const float* __restrict__ wup, unsigned short* __restrict__ Wt) {
    int i = blockIdx.x * 256 + threadIdx.x;          // 64*32*32 = 65536
    int tap = i >> 10, rem = i & 1023, co = rem >> 5, ci = rem & 31;
    Wt[i] = f2b(wup[co * 2048 + ci * 64 + tap]);
}

// ---------------- MFMA upsample (ConvTranspose3d k=4 s=2 as parity tap-GEMM) ----------
__global__ __launch_bounds__(256, 2)
void ups_mfma(const unsigned short* __restrict__ Pt,
              const unsigned short* __restrict__ Wt,
              unsigned short* __restrict__ Ut, int n0)
{
    constexpr int TPW = 11;
    int lin = xcd_lin();
    int z  = lin % 26;
    int nl = lin / 26;
    int lane = threadIdx.x & 63, wave = threadIdx.x >> 6;
    int ln = lane & 15, quad = lane >> 4;
    int pz = z & 1, izb = (z >> 1) + 1;              // padded z index of dz=0 tap
    int py = wave >> 1, px = wave & 1;               // this wave's (oy,ox) parity

    const unsigned short* pbase =
        Pt + (size_t)(n0 + nl) * 2744 * 32 + (size_t)izb * 196 * 32 + quad * 8;

    int nidx[TPW];
    const unsigned short* bptr[TPW];
    #pragma unroll
    for (int t = 0; t < TPW; t++) {
        int n = t * 16 + ln;
        nidx[t] = (n < 169) ? n : 169;               // 169 => inactive lane slot
        int nc = (n < 169) ? n : 168;
        int iy = nc / 13 + 1, ix = nc % 13 + 1;      // padded base (dy=dx=0 tap)
        bptr[t] = pbase + ((size_t)iy * 14 + ix) * 32;
    }
    f32x4 acc[TPW][2];
    #pragma unroll
    for (int t = 0; t < TPW; t++) {
        acc[t][0] = (f32x4){0.f, 0.f, 0.f, 0.f};
        acc[t][1] = (f32x4){0.f, 0.f, 0.f, 0.f};
    }

    #pragma unroll 1
    for (int tap = 0; tap < 8; tap++) {
        int dz = tap >> 2, dy = (tap >> 1) & 1, dx = tap & 1;
        int ptap = (pz + 2 * dz) * 16 + (py + 2 * dy) * 4 + (px + 2 * dx);
        const unsigned short* wp = Wt + ptap * 1024 + ln * 32 + quad * 8;
        bf16x8 Af0 = *(const bf16x8*)wp;             // co tile 0
        bf16x8 Af1 = *(const bf16x8*)(wp + 512);     // co tile 1
        int off = -((dz * 196 + dy * 14 + dx) * 32); // step back into the halo
        #pragma unroll
        for (int t = 0; t < TPW; t++) {
            bf16x8 Bf = *(const bf16x8*)(bptr[t] + off);
            acc[t][0] = __builtin_amdgcn_mfma_f32_16x16x32_bf16(Af0, Bf, acc[t][0], 0, 0, 0);
            acc[t][1] = __builtin_amdgcn_mfma_f32_16x16x32_bf16(Af1, Bf, acc[t][1], 0, 0, 0);
        }
    }

    #pragma unroll
    for (int t = 0; t < TPW; t++) {
        if (nidx[t] >= 169) continue;
        int oy = py + 2 * (nidx[t] / 13);
        int ox = px + 2 * (nidx[t] % 13);
        unsigned short* o = Ut +
            ((size_t)nl * 17576 + (size_t)z * 676 + oy * 26 + ox) * 32 + quad * 4;
        *(ushort4*)o = make_ushort4(f2b(acc[t][0][0]), f2b(acc[t][0][1]),
                                    f2b(acc[t][0][2]), f2b(acc[t][0][3]));
        *(ushort4*)(o + 16) = make_ushort4(f2b(acc[t][1][0]), f2b(acc[t][1][1]),
                                           f2b(acc[t][1][2]), f2b(acc[t][1][3]));
    }
}

// ---------------- weight prep: w[co][ci][27] f32 -> Wt[tap][co][ci] bf16 ----------
__global__ void wprep(const float* __restrict__ w, unsigned short* __restrict__ Wt,
                      int wstride) {
    int i = blockIdx.x * 256 + threadIdx.x;
    if (i >= 27648) return;
    int tap = i >> 10, rem = i & 1023, co = rem >> 5, ci = rem & 31;
    Wt[i] = f2b(w[co * wstride + ci * 27 + tap]);
}

// ---------------- tsdf bias volume: V[zz][yy][xx][co] bf16 (72^3) ----------------
__global__ __launch_bounds__(128)
void vkern(const float* __restrict__ tsdf, const float* __restrict__ w_c0,
           unsigned short* __restrict__ V) {
    int yy = blockIdx.x % 72, zz = blockIdx.x / 72;
    int xx = threadIdx.x;
    if (xx >= 72) return;
    float tv[27];
    #pragma unroll
    for (int kz = 0; kz < 3; kz++)
    #pragma unroll
    for (int ky = 0; ky < 3; ky++)
    #pragma unroll
    for (int kx = 0; kx < 3; kx++)
        tv[kz * 9 + ky * 3 + kx] = tsdf[(size_t)(zz + kz) * 5476 + (yy + ky) * 74 + (xx + kx)];
    unsigned short* o = V + (((size_t)zz * 72 + yy) * 72 + xx) * 32;
    for (int co = 0; co < 32; co++) {
        float a = 0.f;
        const float* wc = w_c0 + co * 891 + 864;   // tsdf channel (ci=32) taps
        #pragma unroll
        for (int j = 0; j < 27; j++) a += tv[j] * wc[j];
        o[co] = f2b(a);
    }
}

// ---------------- MFMA tap-GEMM conv with z-slab register reuse ----------------
// Block = (nl, z-slab of 4, tile-group of 8 16-pos tiles). 4 waves x 2 tiles each.
// acc[zc 0..3][tile 0..1][co-tile 0..1]. Loop: (ky,kx) outer, input-z inner;
// each B fragment (zi,ky,kx) feeds MFMAs for kz=0..2 -> zc=j-kz (register reuse).
// MFMA 16x16x32 bf16: A[m=lane&15][k=quad*8+j], B[n=lane&15][k=quad*8+j],
// D[row=quad*4+reg][col=lane&15]  (m=co-in-tile, n=spatial, k=ci).
// MODE 0: bf16 ch-last out | 1: + acc init from V | 2: f32 split-tree scatter out
template<int SIN, int SOUT, int MODE, int TG>
__global__ __launch_bounds__(256, 2)
void conv_mfma(const unsigned short* __restrict__ in_t,
               const unsigned short* __restrict__ Wt,
               const float* __restrict__ gg, const float* __restrict__ bb,
               unsigned short* __restrict__ out_t, float* __restrict__ out_f,
               const unsigned short* __restrict__ V, int n0)
{
    constexpr int NPOS = SOUT * SOUT;
    constexpr int NT = (NPOS + 15) / 16;
    constexpr int ZB = (SOUT + 3) / 4;
    constexpr bool ZEXACT = (SOUT % 4) == 0;
    int lin = xcd_lin();
    int tg = lin % TG;
    int zb = (lin / TG) % ZB;
    int nl = lin / (TG * ZB);
    int z0 = zb * 4;
    int zcnt = ZEXACT ? 4 : ((SOUT - z0) < 4 ? (SOUT - z0) : 4);
    int lane = threadIdx.x & 63, wave = threadIdx.x >> 6;
    int ln = lane & 15, quad = lane >> 4;

    int nidx[2], py[2], px[2];
    const unsigned short* bptr[2];
    const unsigned short* inb = in_t + (size_t)nl * SIN * SIN * SIN * 32;
    #pragma unroll
    for (int t = 0; t < 2; t++) {
        int ti = tg * 8 + wave * 2 + t;
        int n = ti * 16 + ln;
        nidx[t] = (ti < NT && n < NPOS) ? n : NPOS;     // NPOS => inactive
        int nc = (nidx[t] < NPOS) ? nidx[t] : (NPOS - 1);
        py[t] = nc / SOUT; px[t] = nc % SOUT;
        bptr[t] = inb + ((size_t)py[t] * SIN + px[t]) * 32 + quad * 8;
    }

    f32x4 acc[4][2][2];
    if constexpr (MODE == 1) {
        int n = n0 + nl;
        int Ab = (n >> 4) * 16, Bb = ((n >> 2) & 3) * 16, Cb = (n & 3) * 16;
        #pragma unroll
        for (int zc = 0; zc < 4; zc++) {
            int zo = z0 + zc;
            #pragma unroll
            for (int t = 0; t < 2; t++) {
                const unsigned short* vp =
                    V + (((size_t)(Ab + zo) * 72 + (Bb + py[t])) * 72 + (Cb + px[t])) * 32
                      + quad * 4;
                ushort4 v0 = *(const ushort4*)vp;
                ushort4 v1 = *(const ushort4*)(vp + 16);
                acc[zc][t][0][0] = b2f(v0.x); acc[zc][t][0][1] = b2f(v0.y);
                acc[zc][t][0][2] = b2f(v0.z); acc[zc][t][0][3] = b2f(v0.w);
                acc[zc][t][1][0] = b2f(v1.x); acc[zc][t][1][1] = b2f(v1.y);
                acc[zc][t][1][2] = b2f(v1.z); acc[zc][t][1][3] = b2f(v1.w);
            }
        }
    } else {
        #pragma unroll
        for (int zc = 0; zc < 4; zc++)
        #pragma unroll
        for (int t = 0; t < 2; t++)
        #pragma unroll
        for (int c = 0; c < 2; c++)
            acc[zc][t][c] = (f32x4){0.f, 0.f, 0.f, 0.f};
    }

    #pragma unroll 1
    for (int kyx = 0; kyx < 9; kyx++) {
        int ky = kyx / 3, kx = kyx % 3;
        const unsigned short* wp = Wt + (size_t)kyx * 1024 + ln * 32 + quad * 8;
        bf16x8 A[3][2];
        #pragma unroll
        for (int kz = 0; kz < 3; kz++) {
            A[kz][0] = *(const bf16x8*)(wp + (size_t)kz * 9216);
            A[kz][1] = *(const bf16x8*)(wp + (size_t)kz * 9216 + 512);
        }
        size_t xyo = ((size_t)ky * SIN + kx) * 32;
        #pragma unroll
        for (int j = 0; j < 6; j++) {
            int zia = z0 + j;
            int zs = zia < SIN ? zia : SIN - 1;            // clamp (tail slabs)
            size_t off = (size_t)zs * SIN * SIN * 32 + xyo;
            bf16x8 B0 = *(const bf16x8*)(bptr[0] + off);
            bf16x8 B1 = *(const bf16x8*)(bptr[1] + off);
            #pragma unroll
            for (int kz = 0; kz < 3; kz++) {
                constexpr int dummy = 0; (void)dummy;
                int zc = j - kz;                           // compile-time after unroll
                if (zc < 0 || zc >= 4) continue;
                if (ZEXACT || zc < zcnt) {
                    acc[zc][0][0] = __builtin_amdgcn_mfma_f32_16x16x32_bf16(A[kz][0], B0, acc[zc][0][0], 0, 0, 0);
                    acc[zc][0][1] = __builtin_amdgcn_mfma_f32_16x16x32_bf16(A[kz][1], B0, acc[zc][0][1], 0, 0, 0);
                    acc[zc][1][0] = __builtin_amdgcn_mfma_f32_16x16x32_bf16(A[kz][0], B1, acc[zc][1][0], 0, 0, 0);
                    acc[zc][1][1] = __builtin_amdgcn_mfma_f32_16x16x32_bf16(A[kz][1], B1, acc[zc][1][1], 0, 0, 0);
                }
            }
        }
    }

    int cobase = quad * 4;
    f32x4 g0 = *(const f32x4*)(gg + cobase);
    f32x4 g1 = *(const f32x4*)(gg + 16 + cobase);
    f32x4 b0 = *(const f32x4*)(bb + cobase);
    f32x4 b1 = *(const f32x4*)(bb + 16 + cobase);

    #pragma unroll
    for (int zc = 0; zc < 4; zc++) {
        if (!ZEXACT && zc >= zcnt) continue;
        int zo = z0 + zc;
        #pragma unroll
        for (int t = 0; t < 2; t++) {
            if (nidx[t] >= NPOS) continue;
            float v0[4], v1[4];
            #pragma unroll
            for (int r = 0; r < 4; r++) {
                v0[r] = relu_bn(acc[zc][t][0][r], g0[r], b0[r]);
                v1[r] = relu_bn(acc[zc][t][1][r], g1[r], b1[r]);
            }
            if constexpr (MODE != 2) {
                unsigned short* o = out_t +
                    ((size_t)nl * SOUT * SOUT * SOUT + (size_t)zo * NPOS + nidx[t]) * 32 + cobase;
                *(ushort4*)o        = make_ushort4(f2b(v0[0]), f2b(v0[1]), f2b(v0[2]), f2b(v0[3]));
                *(ushort4*)(o + 16) = make_ushort4(f2b(v1[0]), f2b(v1[1]), f2b(v1[2]), f2b(v1[3]));
            } else {
                int n = n0 + nl;
                int oy = py[t], ox = px[t];
                #pragma unroll
                for (int za = 0; za < 2; za++) {
                    int zz = zo - za * 8; if (zz < 0 || zz >= 12) continue;
                    #pragma unroll
                    for (int yb = 0; yb < 2; yb++) {
                        int yy = oy - yb * 8; if (yy < 0 || yy >= 12) continue;
                        #pragma unroll
                        for (int xc = 0; xc < 2; xc++) {
                            int xx = ox - xc * 8; if (xx < 0 || xx >= 12) continue;
                            int s = za * 4 + yb * 2 + xc;
                            float* ob = out_f + ((size_t)n * 8 + s) * 32 * 1728
                                        + zz * 144 + yy * 12 + xx;
                            #pragma unroll
                            for (int r = 0; r < 4; r++) {
                                ob[(size_t)(cobase + r) * 1728]      = v0[r];
                                ob[(size_t)(16 + cobase + r) * 1728] = v1[r];
                            }
                        }
                    }
                }
            }
        }
    }
}

extern "C" void kernel_launch(void* const* d_in, const int* in_sizes, int n_in,
                              void* d_out, int out_size, void* d_ws, size_t ws_size,
                              hipStream_t stream) {
    const float* prev  = (const float*)d_in[0];
    const float* tsdf  = (const float*)d_in[1];
    const float* w_up  = (const float*)d_in[2];
    const float* w_c0  = (const float*)d_in[3];
    const float* g_c0  = (const float*)d_in[4];
    const float* b_c0  = (const float*)d_in[5];
    const float* w_c1  = (const float*)d_in[6];
    const float* g_c1  = (const float*)d_in[7];
    const float* b_c1  = (const float*)d_in[8];
    const float* w_c2  = (const float*)d_in[9];
    const float* g_c2  = (const float*)d_in[10];
    const float* b_c2  = (const float*)d_in[11];
    const float* w_p0  = (const float*)d_in[12];
    const float* g_p0  = (const float*)d_in[13];
    const float* b_p0  = (const float*)d_in[14];
    const float* w_p1  = (const float*)d_in[15];
    const float* g_p1  = (const float*)d_in[16];
    const float* b_p1  = (const float*)d_in[17];
    const float* w_lin = (const float*)d_in[18];
    const float* b_lin = (const float*)d_in[19];

    float* out = (float*)d_out;
    char* wsb  = (char*)d_ws;

    size_t off = 0;
    float* h0 = (float*)(wsb + off);            off += 512000;      // 64*16*125 f32
    unsigned short* Wt0 = (unsigned short*)(wsb + off); off += 55296;
    unsigned short* Wt1 = (unsigned short*)(wsb + off); off += 55296;
    unsigned short* Wt2 = (unsigned short*)(wsb + off); off += 55296;
    unsigned short* V   = (unsigned short*)(wsb + off); off += 23887872; // 72^3*32 bf16
    unsigned short* Pt  = (unsigned short*)(wsb + off); off += 11239424; // 64*14^3*32 bf16
    unsigned short* WupT= (unsigned short*)(wsb + off); off += 131072;   // 64*32*32 bf16
    size_t fixed = off;

    int chunk = 64;
    while (chunk > 1) {
        size_t need = fixed + (size_t)chunk *
            (1124864ull /*U_t*/ + 884736ull /*X0_t*/ + 681472ull /*X1_t*/);
        if (need <= ws_size) break;
        chunk >>= 1;
    }
    unsigned short* U_t = (unsigned short*)(wsb + off); off += (size_t)chunk * 1124864;
    unsigned short* X0t = (unsigned short*)(wsb + off); off += (size_t)chunk * 884736;
    unsigned short* X1t = (unsigned short*)(wsb + off);

    // prediction path + preps
    pred_p0<<<64 * 16, 128, 0, stream>>>(prev, w_p0, g_p0, b_p0, h0);
    pred_p1<<<64, 256, 0, stream>>>(h0, w_p1, g_p1, b_p1, w_lin, b_lin,
                                    out + SUBTREE_FLOATS);
    ptcvt<<<64, 256, 0, stream>>>(prev, Pt);
    wupprep<<<256, 256, 0, stream>>>(w_up, WupT);
    wprep<<<108, 256, 0, stream>>>(w_c0, Wt0, 891);
    wprep<<<108, 256, 0, stream>>>(w_c1, Wt1, 864);
    wprep<<<108, 256, 0, stream>>>(w_c2, Wt2, 864);
    vkern<<<72 * 72, 128, 0, stream>>>(tsdf, w_c0, V);

    for (int n0 = 0; n0 < NBLK; n0 += chunk) {
        ups_mfma<<<chunk * 26, 256, 0, stream>>>(Pt, WupT, U_t, n0);
        // conv0: SOUT=24 -> ZB=6, NT=36 -> TG=5 ; grid = chunk*30
        conv_mfma<26, 24, 1, 5><<<chunk * 30, 256, 0, stream>>>(
            U_t, Wt0, g_c0, b_c0, X0t, nullptr, V, n0);
        // conv1: SOUT=22 -> ZB=6, NT=31 -> TG=4 ; grid = chunk*24
        conv_mfma<24, 22, 0, 4><<<chunk * 24, 256, 0, stream>>>(
            X0t, Wt1, g_c1, b_c1, X1t, nullptr, nullptr, n0);
        // conv2: SOUT=20 -> ZB=5, NT=25 -> TG=4 ; grid = chunk*20
        conv_mfma<22, 20, 2, 4><<<chunk * 20, 256, 0, stream>>>(
            X1t, Wt2, g_c2, b_c2, nullptr, out, nullptr, n0);
    }
}

// Round 6
// 570.115 us; speedup vs baseline: 1.7034x; 1.1401x over previous
//
#include <hip/hip_runtime.h>
#include <math.h>

// Pipeline: prev->bf16 halo transpose (ptcvt) -> MFMA pred_p0 (tap-GEMM + fused
// BN/ReLU/pool) -> pred_p1 (f32) | MFMA upsample -> MFMA tap-GEMM convs on
// channel-last bf16 (f32 accum), conv0 init from tsdf bias volume V, conv2 fused
// split-tree scatter (f32 out).
// R6: fix pred_p0m epilogue (400 work items vs 256 threads -> strided loop).
#define NBLK 64
#define SUBTREE_FLOATS (512ull*32ull*1728ull)   // 28,311,552

typedef __attribute__((ext_vector_type(8))) short bf16x8;   // 8 bf16 (4 VGPR)
typedef __attribute__((ext_vector_type(4))) float f32x4;    // MFMA acc

__device__ __forceinline__ unsigned short f2b(float f) {    // f32->bf16 RNE
    unsigned u = __float_as_uint(f);
    u = u + 0x7FFFu + ((u >> 16) & 1u);
    return (unsigned short)(u >> 16);
}
__device__ __forceinline__ float b2f(unsigned short h) {
    return __uint_as_float(((unsigned)h) << 16);
}
__device__ __forceinline__ float relu_bn(float acc, float g, float b) {
    float s = g * rsqrtf(1.0f + 1e-5f);
    float v = acc * s + b;
    return v > 0.f ? v : 0.f;
}
// XCD-bijective remap: contiguous lin-chunk per XCD (hw: XCD = blockIdx % 8).
__device__ __forceinline__ int xcd_lin() {
    int bid = blockIdx.x, nwg = gridDim.x;
    if ((nwg & 7) == 0) {
        int per = nwg >> 3;
        return (bid & 7) * per + (bid >> 3);
    }
    return bid;
}

// ---------------- prev -> channel-last bf16 with 1-voxel zero halo ----------------
// Pt[n][z+1][y+1][x+1][ci] bf16, padded dims 14^3 (indices 0 and 13 are zero).
__global__ __launch_bounds__(256)
void ptcvt(const float* __restrict__ prev, unsigned short* __restrict__ Pt) {
    int n = blockIdx.x;
    const float* pb = prev + (size_t)n * 32 * 1728;
    unsigned short* ob = Pt + (size_t)n * 2744 * 32;
    for (int pos = threadIdx.x; pos < 2744; pos += 256) {
        int x = pos % 14, y = (pos / 14) % 14, zz = pos / 196;
        ushort4* o = (ushort4*)(ob + (size_t)pos * 32);
        if (x >= 1 && x <= 12 && y >= 1 && y <= 12 && zz >= 1 && zz <= 12) {
            int src = (zz - 1) * 144 + (y - 1) * 12 + (x - 1);
            unsigned short v[32];
            #pragma unroll
            for (int ci = 0; ci < 32; ci++) v[ci] = f2b(pb[(size_t)ci * 1728 + src]);
            #pragma unroll
            for (int j = 0; j < 8; j++)
                o[j] = make_ushort4(v[4 * j], v[4 * j + 1], v[4 * j + 2], v[4 * j + 3]);
        } else {
            #pragma unroll
            for (int j = 0; j < 8; j++) o[j] = make_ushort4(0, 0, 0, 0);
        }
    }
}

// ---------------- pred p0 weight prep: w_p0[co16][ci32][27] -> Wp[tap][co16][ci32] ----
__global__ void wp0prep(const float* __restrict__ w, unsigned short* __restrict__ Wt) {
    int i = blockIdx.x * 256 + threadIdx.x;          // 27*512 = 13824
    if (i >= 13824) return;
    int tap = i >> 9, rem = i & 511, co = rem >> 5, ci = rem & 31;
    Wt[i] = f2b(w[co * 864 + ci * 27 + tap]);
}

// ---------------- MFMA pred_p0: conv(32->16,k3) on Pt + BN/ReLU + 2x2x2 maxpool ----
// Block = (n, z-slab of 4 outputs). 4 waves x 2 tiles cover 100 xy-positions.
// acc[zc][tile]; (ky,kx) outer, input-z inner, B reused across 3 kz.
// Epilogue: z-pair max in reg, x-pair max via shfl_xor(1) (pairs never straddle
// 16-lane tiles: pos=y*10+x, y*10 even), y-pair max via LDS. Writes h0 f32.
__global__ __launch_bounds__(256, 2)
void pred_p0m(const unsigned short* __restrict__ Pt,
              const unsigned short* __restrict__ Wp,
              const float* __restrict__ g, const float* __restrict__ b,
              float* __restrict__ h0) {
    int lin = xcd_lin();
    int zb = lin % 3;
    int n  = lin / 3;
    int z0 = zb * 4;
    int zcnt = (zb == 2) ? 2 : 4;                    // outputs z0..z0+zcnt-1 (of 10)
    int lane = threadIdx.x & 63, wave = threadIdx.x >> 6;
    int ln = lane & 15, quad = lane >> 4;

    __shared__ float pool[2][16][10][5];

    const unsigned short* inb = Pt + (size_t)n * 2744 * 32;
    int nidx[2];
    const unsigned short* bptr[2];
    #pragma unroll
    for (int t = 0; t < 2; t++) {
        int ti = wave * 2 + t;
        int p = ti * 16 + ln;
        nidx[t] = (p < 100) ? p : 100;
        int pc = (p < 100) ? p : 99;
        int py = pc / 10, px = pc % 10;
        bptr[t] = inb + ((size_t)(py + 1) * 14 + (px + 1)) * 32 + quad * 8;
    }
    f32x4 acc[4][2];
    #pragma unroll
    for (int zc = 0; zc < 4; zc++)
    #pragma unroll
    for (int t = 0; t < 2; t++)
        acc[zc][t] = (f32x4){0.f, 0.f, 0.f, 0.f};

    #pragma unroll 1
    for (int kyx = 0; kyx < 9; kyx++) {
        bf16x8 A[3];
        #pragma unroll
        for (int kz = 0; kz < 3; kz++)
            A[kz] = *(const bf16x8*)(Wp + (size_t)(kz * 9 + kyx) * 512 + ln * 32 + quad * 8);
        size_t xyo = ((size_t)(kyx / 3) * 14 + (kyx % 3)) * 32;
        #pragma unroll
        for (int j = 0; j < 6; j++) {
            int zia = z0 + j;
            int zs = zia < 12 ? zia : 12;            // clamp into halo (zero)
            size_t off = (size_t)(zs + 1) * 196 * 32 + xyo;
            bf16x8 B0 = *(const bf16x8*)(bptr[0] + off);
            bf16x8 B1 = *(const bf16x8*)(bptr[1] + off);
            #pragma unroll
            for (int kz = 0; kz < 3; kz++) {
                int zc = j - kz;                     // compile-time after unroll
                if (zc < 0 || zc >= 4) continue;     // store-side guards zc>=zcnt
                acc[zc][0] = __builtin_amdgcn_mfma_f32_16x16x32_bf16(A[kz], B0, acc[zc][0], 0, 0, 0);
                acc[zc][1] = __builtin_amdgcn_mfma_f32_16x16x32_bf16(A[kz], B1, acc[zc][1], 0, 0, 0);
            }
        }
    }

    f32x4 gv = *(const f32x4*)(g + quad * 4);
    f32x4 bv = *(const f32x4*)(b + quad * 4);
    int zpcnt = zcnt >> 1;
    #pragma unroll
    for (int zp = 0; zp < 2; zp++) {
        if (zp >= zpcnt) continue;                   // wave-uniform
        #pragma unroll
        for (int t = 0; t < 2; t++) {
            #pragma unroll
            for (int r = 0; r < 4; r++) {
                float a0 = relu_bn(acc[2 * zp][t][r], gv[r], bv[r]);
                float a1 = relu_bn(acc[2 * zp + 1][t][r], gv[r], bv[r]);
                float v = fmaxf(a0, a1);
                v = fmaxf(v, __shfl_xor(v, 1));
                if (nidx[t] < 100 && !(ln & 1)) {
                    int pos = nidx[t];
                    pool[zp][quad * 4 + r][pos / 10][(pos % 10) >> 1] = v;
                }
            }
        }
    }
    __syncthreads();
    for (int t = threadIdx.x; t < 400; t += 256) {
        int co = t / 25, r2 = t % 25, py = r2 / 5, px = r2 % 5;
        for (int zp = 0; zp < zpcnt; zp++) {
            float v = fmaxf(pool[zp][co][2 * py][px], pool[zp][co][2 * py + 1][px]);
            h0[((size_t)n * 16 + co) * 125 + (zb * 2 + zp) * 25 + py * 5 + px] = v;
        }
    }
}

// ---------------- pred p1 (f32, unchanged) ----------------
__global__ void pred_p1(const float* __restrict__ h0, const float* __restrict__ w,
                        const float* __restrict__ g, const float* __restrict__ b,
                        const float* __restrict__ wlin, const float* __restrict__ blin,
                        float* __restrict__ pred_out) {
    int n = blockIdx.x;
    __shared__ float conv[216];
    __shared__ float pooled[8];
    int t = threadIdx.x;
    if (t < 216) {
        int co = t / 27, r = t % 27;
        int oz = r / 9, oy = (r / 3) % 3, ox = r % 3;
        float acc = 0.f;
        for (int ci = 0; ci < 16; ci++) {
            const float* hc = h0 + (n * 16 + ci) * 125 + oz * 25 + oy * 5 + ox;
            const float* wc = w + (co * 16 + ci) * 27;
            #pragma unroll
            for (int kz = 0; kz < 3; kz++)
            #pragma unroll
            for (int ky = 0; ky < 3; ky++)
            #pragma unroll
            for (int kx = 0; kx < 3; kx++)
                acc += hc[kz * 25 + ky * 5 + kx] * wc[kz * 9 + ky * 3 + kx];
        }
        conv[t] = relu_bn(acc, g[co], b[co]);
    }
    __syncthreads();
    if (t < 8) {
        float m = -INFINITY;
        for (int dz = 0; dz < 2; dz++)
        for (int dy = 0; dy < 2; dy++)
        for (int dx = 0; dx < 2; dx++)
            m = fmaxf(m, conv[t * 27 + dz * 9 + dy * 3 + dx]);
        pooled[t] = m;
    }
    __syncthreads();
    if (t < 3) {
        float acc = blin[t];
        #pragma unroll
        for (int j = 0; j < 8; j++) acc += pooled[j] * wlin[t * 8 + j];
        pred_out[n * 3 + t] = acc;
    }
}

// ---------------- upsample weight prep ----------------
__global__ void wupprep(const float* __restrict__ wup, unsigned short* __restrict__ Wt) {
    int i = blockIdx.x * 256 + threadIdx.x;          // 64*32*32 = 65536
    int tap = i >> 10, rem = i & 1023, co = rem >> 5, ci = rem & 31;
    Wt[i] = f2b(wup[co * 2048 + ci * 64 + tap]);
}

// ---------------- MFMA upsample (ConvTranspose3d k=4 s=2 as parity tap-GEMM) ----------
__global__ __launch_bounds__(256, 2)
void ups_mfma(const unsigned short* __restrict__ Pt,
              const unsigned short* __restrict__ Wt,
              unsigned short* __restrict__ Ut, int n0)
{
    constexpr int TPW = 11;
    int lin = xcd_lin();
    int z  = lin % 26;
    int nl = lin / 26;
    int lane = threadIdx.x & 63, wave = threadIdx.x >> 6;
    int ln = lane & 15, quad = lane >> 4;
    int pz = z & 1, izb = (z >> 1) + 1;              // padded z index of dz=0 tap
    int py = wave >> 1, px = wave & 1;               // this wave's (oy,ox) parity

    const unsigned short* pbase =
        Pt + (size_t)(n0 + nl) * 2744 * 32 + (size_t)izb * 196 * 32 + quad * 8;

    int nidx[TPW];
    const unsigned short* bptr[TPW];
    #pragma unroll
    for (int t = 0; t < TPW; t++) {
        int n = t * 16 + ln;
        nidx[t] = (n < 169) ? n : 169;               // 169 => inactive lane slot
        int nc = (n < 169) ? n : 168;
        int iy = nc / 13 + 1, ix = nc % 13 + 1;      // padded base (dy=dx=0 tap)
        bptr[t] = pbase + ((size_t)iy * 14 + ix) * 32;
    }
    f32x4 acc[TPW][2];
    #pragma unroll
    for (int t = 0; t < TPW; t++) {
        acc[t][0] = (f32x4){0.f, 0.f, 0.f, 0.f};
        acc[t][1] = (f32x4){0.f, 0.f, 0.f, 0.f};
    }

    #pragma unroll 1
    for (int tap = 0; tap < 8; tap++) {
        int dz = tap >> 2, dy = (tap >> 1) & 1, dx = tap & 1;
        int ptap = (pz + 2 * dz) * 16 + (py + 2 * dy) * 4 + (px + 2 * dx);
        const unsigned short* wp = Wt + ptap * 1024 + ln * 32 + quad * 8;
        bf16x8 Af0 = *(const bf16x8*)wp;             // co tile 0
        bf16x8 Af1 = *(const bf16x8*)(wp + 512);     // co tile 1
        int off = -((dz * 196 + dy * 14 + dx) * 32); // step back into the halo
        #pragma unroll
        for (int t = 0; t < TPW; t++) {
            bf16x8 Bf = *(const bf16x8*)(bptr[t] + off);
            acc[t][0] = __builtin_amdgcn_mfma_f32_16x16x32_bf16(Af0, Bf, acc[t][0], 0, 0, 0);
            acc[t][1] = __builtin_amdgcn_mfma_f32_16x16x32_bf16(Af1, Bf, acc[t][1], 0, 0, 0);
        }
    }

    #pragma unroll
    for (int t = 0; t < TPW; t++) {
        if (nidx[t] >= 169) continue;
        int oy = py + 2 * (nidx[t] / 13);
        int ox = px + 2 * (nidx[t] % 13);
        unsigned short* o = Ut +
            ((size_t)nl * 17576 + (size_t)z * 676 + oy * 26 + ox) * 32 + quad * 4;
        *(ushort4*)o = make_ushort4(f2b(acc[t][0][0]), f2b(acc[t][0][1]),
                                    f2b(acc[t][0][2]), f2b(acc[t][0][3]));
        *(ushort4*)(o + 16) = make_ushort4(f2b(acc[t][1][0]), f2b(acc[t][1][1]),
                                           f2b(acc[t][1][2]), f2b(acc[t][1][3]));
    }
}

// ---------------- weight prep: w[co][ci][27] f32 -> Wt[tap][co][ci] bf16 ----------
__global__ void wprep(const float* __restrict__ w, unsigned short* __restrict__ Wt,
                      int wstride) {
    int i = blockIdx.x * 256 + threadIdx.x;
    if (i >= 27648) return;
    int tap = i >> 10, rem = i & 1023, co = rem >> 5, ci = rem & 31;
    Wt[i] = f2b(w[co * wstride + ci * 27 + tap]);
}

// ---------------- tsdf bias volume: V[zz][yy][xx][co] bf16 (72^3) ----------------
__global__ __launch_bounds__(128)
void vkern(const float* __restrict__ tsdf, const float* __restrict__ w_c0,
           unsigned short* __restrict__ V) {
    int yy = blockIdx.x % 72, zz = blockIdx.x / 72;
    int xx = threadIdx.x;
    if (xx >= 72) return;
    float tv[27];
    #pragma unroll
    for (int kz = 0; kz < 3; kz++)
    #pragma unroll
    for (int ky = 0; ky < 3; ky++)
    #pragma unroll
    for (int kx = 0; kx < 3; kx++)
        tv[kz * 9 + ky * 3 + kx] = tsdf[(size_t)(zz + kz) * 5476 + (yy + ky) * 74 + (xx + kx)];
    unsigned short* o = V + (((size_t)zz * 72 + yy) * 72 + xx) * 32;
    for (int co = 0; co < 32; co++) {
        float a = 0.f;
        const float* wc = w_c0 + co * 891 + 864;   // tsdf channel (ci=32) taps
        #pragma unroll
        for (int j = 0; j < 27; j++) a += tv[j] * wc[j];
        o[co] = f2b(a);
    }
}

// ---------------- MFMA tap-GEMM conv with z-slab register reuse ----------------
// Block = (nl, z-slab of 4, tile-group of 8 16-pos tiles). 4 waves x 2 tiles each.
// acc[zc 0..3][tile 0..1][co-tile 0..1]. Loop: (ky,kx) outer, input-z inner;
// each B fragment (zi,ky,kx) feeds MFMAs for kz=0..2 -> zc=j-kz (register reuse).
// MODE 0: bf16 ch-last out | 1: + acc init from V | 2: f32 split-tree scatter out
template<int SIN, int SOUT, int MODE, int TG>
__global__ __launch_bounds__(256, 2)
void conv_mfma(const unsigned short* __restrict__ in_t,
               const unsigned short* __restrict__ Wt,
               const float* __restrict__ gg, const float* __restrict__ bb,
               unsigned short* __restrict__ out_t, float* __restrict__ out_f,
               const unsigned short* __restrict__ V, int n0)
{
    constexpr int NPOS = SOUT * SOUT;
    constexpr int NT = (NPOS + 15) / 16;
    constexpr int ZB = (SOUT + 3) / 4;
    constexpr bool ZEXACT = (SOUT % 4) == 0;
    int lin = xcd_lin();
    int tg = lin % TG;
    int zb = (lin / TG) % ZB;
    int nl = lin / (TG * ZB);
    int z0 = zb * 4;
    int zcnt = ZEXACT ? 4 : ((SOUT - z0) < 4 ? (SOUT - z0) : 4);
    int lane = threadIdx.x & 63, wave = threadIdx.x >> 6;
    int ln = lane & 15, quad = lane >> 4;

    int nidx[2], py[2], px[2];
    const unsigned short* bptr[2];
    const unsigned short* inb = in_t + (size_t)nl * SIN * SIN * SIN * 32;
    #pragma unroll
    for (int t = 0; t < 2; t++) {
        int ti = tg * 8 + wave * 2 + t;
        int n = ti * 16 + ln;
        nidx[t] = (ti < NT && n < NPOS) ? n : NPOS;     // NPOS => inactive
        int nc = (nidx[t] < NPOS) ? nidx[t] : (NPOS - 1);
        py[t] = nc / SOUT; px[t] = nc % SOUT;
        bptr[t] = inb + ((size_t)py[t] * SIN + px[t]) * 32 + quad * 8;
    }

    f32x4 acc[4][2][2];
    if constexpr (MODE == 1) {
        int n = n0 + nl;
        int Ab = (n >> 4) * 16, Bb = ((n >> 2) & 3) * 16, Cb = (n & 3) * 16;
        #pragma unroll
        for (int zc = 0; zc < 4; zc++) {
            int zo = z0 + zc;
            #pragma unroll
            for (int t = 0; t < 2; t++) {
                const unsigned short* vp =
                    V + (((size_t)(Ab + zo) * 72 + (Bb + py[t])) * 72 + (Cb + px[t])) * 32
                      + quad * 4;
                ushort4 v0 = *(const ushort4*)vp;
                ushort4 v1 = *(const ushort4*)(vp + 16);
                acc[zc][t][0][0] = b2f(v0.x); acc[zc][t][0][1] = b2f(v0.y);
                acc[zc][t][0][2] = b2f(v0.z); acc[zc][t][0][3] = b2f(v0.w);
                acc[zc][t][1][0] = b2f(v1.x); acc[zc][t][1][1] = b2f(v1.y);
                acc[zc][t][1][2] = b2f(v1.z); acc[zc][t][1][3] = b2f(v1.w);
            }
        }
    } else {
        #pragma unroll
        for (int zc = 0; zc < 4; zc++)
        #pragma unroll
        for (int t = 0; t < 2; t++)
        #pragma unroll
        for (int c = 0; c < 2; c++)
            acc[zc][t][c] = (f32x4){0.f, 0.f, 0.f, 0.f};
    }

    #pragma unroll 1
    for (int kyx = 0; kyx < 9; kyx++) {
        int ky = kyx / 3, kx = kyx % 3;
        const unsigned short* wp = Wt + (size_t)kyx * 1024 + ln * 32 + quad * 8;
        bf16x8 A[3][2];
        #pragma unroll
        for (int kz = 0; kz < 3; kz++) {
            A[kz][0] = *(const bf16x8*)(wp + (size_t)kz * 9216);
            A[kz][1] = *(const bf16x8*)(wp + (size_t)kz * 9216 + 512);
        }
        size_t xyo = ((size_t)ky * SIN + kx) * 32;
        #pragma unroll
        for (int j = 0; j < 6; j++) {
            int zia = z0 + j;
            int zs = zia < SIN ? zia : SIN - 1;            // clamp (tail slabs)
            size_t off = (size_t)zs * SIN * SIN * 32 + xyo;
            bf16x8 B0 = *(const bf16x8*)(bptr[0] + off);
            bf16x8 B1 = *(const bf16x8*)(bptr[1] + off);
            #pragma unroll
            for (int kz = 0; kz < 3; kz++) {
                int zc = j - kz;                           // compile-time after unroll
                if (zc < 0 || zc >= 4) continue;
                if (ZEXACT || zc < zcnt) {
                    acc[zc][0][0] = __builtin_amdgcn_mfma_f32_16x16x32_bf16(A[kz][0], B0, acc[zc][0][0], 0, 0, 0);
                    acc[zc][0][1] = __builtin_amdgcn_mfma_f32_16x16x32_bf16(A[kz][1], B0, acc[zc][0][1], 0, 0, 0);
                    acc[zc][1][0] = __builtin_amdgcn_mfma_f32_16x16x32_bf16(A[kz][0], B1, acc[zc][1][0], 0, 0, 0);
                    acc[zc][1][1] = __builtin_amdgcn_mfma_f32_16x16x32_bf16(A[kz][1], B1, acc[zc][1][1], 0, 0, 0);
                }
            }
        }
    }

    int cobase = quad * 4;
    f32x4 g0 = *(const f32x4*)(gg + cobase);
    f32x4 g1 = *(const f32x4*)(gg + 16 + cobase);
    f32x4 b0 = *(const f32x4*)(bb + cobase);
    f32x4 b1 = *(const f32x4*)(bb + 16 + cobase);

    #pragma unroll
    for (int zc = 0; zc < 4; zc++) {
        if (!ZEXACT && zc >= zcnt) continue;
        int zo = z0 + zc;
        #pragma unroll
        for (int t = 0; t < 2; t++) {
            if (nidx[t] >= NPOS) continue;
            float v0[4], v1[4];
            #pragma unroll
            for (int r = 0; r < 4; r++) {
                v0[r] = relu_bn(acc[zc][t][0][r], g0[r], b0[r]);
                v1[r] = relu_bn(acc[zc][t][1][r], g1[r], b1[r]);
            }
            if constexpr (MODE != 2) {
                unsigned short* o = out_t +
                    ((size_t)nl * SOUT * SOUT * SOUT + (size_t)zo * NPOS + nidx[t]) * 32 + cobase;
                *(ushort4*)o        = make_ushort4(f2b(v0[0]), f2b(v0[1]), f2b(v0[2]), f2b(v0[3]));
                *(ushort4*)(o + 16) = make_ushort4(f2b(v1[0]), f2b(v1[1]), f2b(v1[2]), f2b(v1[3]));
            } else {
                int n = n0 + nl;
                int oy = py[t], ox = px[t];
                #pragma unroll
                for (int za = 0; za < 2; za++) {
                    int zz = zo - za * 8; if (zz < 0 || zz >= 12) continue;
                    #pragma unroll
                    for (int yb = 0; yb < 2; yb++) {
                        int yy = oy - yb * 8; if (yy < 0 || yy >= 12) continue;
                        #pragma unroll
                        for (int xc = 0; xc < 2; xc++) {
                            int xx = ox - xc * 8; if (xx < 0 || xx >= 12) continue;
                            int s = za * 4 + yb * 2 + xc;
                            float* ob = out_f + ((size_t)n * 8 + s) * 32 * 1728
                                        + zz * 144 + yy * 12 + xx;
                            #pragma unroll
                            for (int r = 0; r < 4; r++) {
                                ob[(size_t)(cobase + r) * 1728]      = v0[r];
                                ob[(size_t)(16 + cobase + r) * 1728] = v1[r];
                            }
                        }
                    }
                }
            }
        }
    }
}

extern "C" void kernel_launch(void* const* d_in, const int* in_sizes, int n_in,
                              void* d_out, int out_size, void* d_ws, size_t ws_size,
                              hipStream_t stream) {
    const float* prev  = (const float*)d_in[0];
    const float* tsdf  = (const float*)d_in[1];
    const float* w_up  = (const float*)d_in[2];
    const float* w_c0  = (const float*)d_in[3];
    const float* g_c0  = (const float*)d_in[4];
    const float* b_c0  = (const float*)d_in[5];
    const float* w_c1  = (const float*)d_in[6];
    const float* g_c1  = (const float*)d_in[7];
    const float* b_c1  = (const float*)d_in[8];
    const float* w_c2  = (const float*)d_in[9];
    const float* g_c2  = (const float*)d_in[10];
    const float* b_c2  = (const float*)d_in[11];
    const float* w_p0  = (const float*)d_in[12];
    const float* g_p0  = (const float*)d_in[13];
    const float* b_p0  = (const float*)d_in[14];
    const float* w_p1  = (const float*)d_in[15];
    const float* g_p1  = (const float*)d_in[16];
    const float* b_p1  = (const float*)d_in[17];
    const float* w_lin = (const float*)d_in[18];
    const float* b_lin = (const float*)d_in[19];

    float* out = (float*)d_out;
    char* wsb  = (char*)d_ws;

    size_t off = 0;
    float* h0 = (float*)(wsb + off);            off += 512000;      // 64*16*125 f32
    unsigned short* Wt0 = (unsigned short*)(wsb + off); off += 55296;
    unsigned short* Wt1 = (unsigned short*)(wsb + off); off += 55296;
    unsigned short* Wt2 = (unsigned short*)(wsb + off); off += 55296;
    unsigned short* V   = (unsigned short*)(wsb + off); off += 23887872; // 72^3*32 bf16
    unsigned short* Pt  = (unsigned short*)(wsb + off); off += 11239424; // 64*14^3*32 bf16
    unsigned short* WupT= (unsigned short*)(wsb + off); off += 131072;   // 64*32*32 bf16
    unsigned short* Wp0 = (unsigned short*)(wsb + off); off += 27648;    // 27*16*32 bf16
    size_t fixed = off;

    int chunk = 64;
    while (chunk > 1) {
        size_t need = fixed + (size_t)chunk *
            (1124864ull /*U_t*/ + 884736ull /*X0_t*/ + 681472ull /*X1_t*/);
        if (need <= ws_size) break;
        chunk >>= 1;
    }
    unsigned short* U_t = (unsigned short*)(wsb + off); off += (size_t)chunk * 1124864;
    unsigned short* X0t = (unsigned short*)(wsb + off); off += (size_t)chunk * 884736;
    unsigned short* X1t = (unsigned short*)(wsb + off);

    // preps + prediction path (pred_p0m consumes Pt + Wp0)
    ptcvt<<<64, 256, 0, stream>>>(prev, Pt);
    wp0prep<<<54, 256, 0, stream>>>(w_p0, Wp0);
    pred_p0m<<<192, 256, 0, stream>>>(Pt, Wp0, g_p0, b_p0, h0);
    pred_p1<<<64, 256, 0, stream>>>(h0, w_p1, g_p1, b_p1, w_lin, b_lin,
                                    out + SUBTREE_FLOATS);
    wupprep<<<256, 256, 0, stream>>>(w_up, WupT);
    wprep<<<108, 256, 0, stream>>>(w_c0, Wt0, 891);
    wprep<<<108, 256, 0, stream>>>(w_c1, Wt1, 864);
    wprep<<<108, 256, 0, stream>>>(w_c2, Wt2, 864);
    vkern<<<72 * 72, 128, 0, stream>>>(tsdf, w_c0, V);

    for (int n0 = 0; n0 < NBLK; n0 += chunk) {
        ups_mfma<<<chunk * 26, 256, 0, stream>>>(Pt, WupT, U_t, n0);
        // conv0: SOUT=24 -> ZB=6, NT=36 -> TG=5 ; grid = chunk*30
        conv_mfma<26, 24, 1, 5><<<chunk * 30, 256, 0, stream>>>(
            U_t, Wt0, g_c0, b_c0, X0t, nullptr, V, n0);
        // conv1: SOUT=22 -> ZB=6, NT=31 -> TG=4 ; grid = chunk*24
        conv_mfma<24, 22, 0, 4><<<chunk * 24, 256, 0, stream>>>(
            X0t, Wt1, g_c1, b_c1, X1t, nullptr, nullptr, n0);
        // conv2: SOUT=20 -> ZB=5, NT=25 -> TG=4 ; grid = chunk*20
        conv_mfma<22, 20, 2, 4><<<chunk * 20, 256, 0, stream>>>(
            X1t, Wt2, g_c2, b_c2, nullptr, out, nullptr, n0);
    }
}